// Round 1
// baseline (1451.620 us; speedup 1.0000x reference)
//
#include <hip/hip_runtime.h>
#include <hip/hip_bf16.h>

#define NN 50000
#define EE 600000
#define DD 128
#define LL 4
#define CC 10
#define GG 512
#define BN_EPS 1e-5f

// ---------------- CSR build ----------------

__global__ void hist_kernel(const int* __restrict__ idx, int* __restrict__ cnt, int n) {
    int i = blockIdx.x * blockDim.x + threadIdx.x;
    if (i < n) atomicAdd(&cnt[idx[i]], 1);
}

// single-block exclusive scan, n <= 1024*chunk; writes out[0..n] (out[n]=total),
// optionally duplicates out[0..n-1] into out2 (cursor for CSR fill)
__global__ __launch_bounds__(1024) void scan_excl(const int* __restrict__ in,
                                                  int* __restrict__ out,
                                                  int* __restrict__ out2, int n) {
    __shared__ int red[1024];
    int tid = threadIdx.x;
    int chunk = (n + 1023) / 1024;
    int beg = tid * chunk;
    int end = min(n, beg + chunk);
    int s = 0;
    for (int i = beg; i < end; ++i) s += in[i];
    red[tid] = s;
    __syncthreads();
    for (int off = 1; off < 1024; off <<= 1) {
        int v = (tid >= off) ? red[tid - off] : 0;
        __syncthreads();
        red[tid] += v;
        __syncthreads();
    }
    int run = red[tid] - s;  // exclusive prefix over threads
    for (int i = beg; i < end; ++i) {
        int v = in[i];
        out[i] = run;
        if (out2) out2[i] = run;
        run += v;
    }
    if (tid == 1023) out[n] = red[1023];
}

__global__ void fill_csr(const int* __restrict__ src, const int* __restrict__ dst,
                         int* __restrict__ cursor, int* __restrict__ csr) {
    int e = blockIdx.x * blockDim.x + threadIdx.x;
    if (e < EE) {
        int d = dst[e];
        int pos = atomicAdd(&cursor[d], 1);
        csr[pos] = src[e];
    }
}

// ---------------- aggregation: out[n] = h[n] + sum_{src in csr row n} h[src] ----------------

__global__ __launch_bounds__(256) void aggregate(const float* __restrict__ h,
                                                 const int* __restrict__ rowptr,
                                                 const int* __restrict__ csr,
                                                 float* __restrict__ out) {
    int node = blockIdx.x * 4 + (threadIdx.x >> 6);  // one wave (64 lanes) per node
    if (node >= NN) return;
    int lane = threadIdx.x & 63;
    float2 acc = ((const float2*)(h + (size_t)node * DD))[lane];
    int beg = rowptr[node], end = rowptr[node + 1];
    for (int e = beg; e < end; ++e) {
        int s = csr[e];
        float2 v = ((const float2*)(h + (size_t)s * DD))[lane];
        acc.x += v.x;
        acc.y += v.y;
    }
    ((float2*)(out + (size_t)node * DD))[lane] = acc;
}

// ---------------- GEMM: Out[r][j] = (bnrelu?)(Z[r][k]) @ W[k][j] + bias[j], + column stats ----------------

__global__ __launch_bounds__(512) void gemm_kernel(
    const float* __restrict__ Z, const float* __restrict__ W,
    const float* __restrict__ bias,
    const float* __restrict__ bnStatsIn,  // null => raw input; else apply BN(gamma,beta)+ReLU on load
    const float* __restrict__ gamma, const float* __restrict__ beta,
    float* __restrict__ Out,
    float* __restrict__ statsOut)         // [0..127]=colsum, [128..255]=colsumsq
{
    __shared__ float Ws[DD * DD];   // 64 KB
    __shared__ float Zs[64 * DD];   // 32 KB
    __shared__ float AbnS[DD], BbnS[DD];
    const int tid = threadIdx.x;
    const int row0 = blockIdx.x * 64;
    const bool doBn = (bnStatsIn != nullptr);

    if (doBn) {
        if (tid < DD) {
            float mu = bnStatsIn[tid] * (1.0f / NN);
            float var = bnStatsIn[DD + tid] * (1.0f / NN) - mu * mu;
            float A = gamma[tid] * rsqrtf(var + BN_EPS);
            AbnS[tid] = A;
            BbnS[tid] = beta[tid] - mu * A;
        }
        __syncthreads();
    }

    const float4* W4 = (const float4*)W;
    float4* Ws4 = (float4*)Ws;
#pragma unroll
    for (int i = 0; i < 8; ++i) Ws4[tid + i * 512] = W4[tid + i * 512];

    float4* Zs4 = (float4*)Zs;
#pragma unroll
    for (int i = 0; i < 4; ++i) {
        int lin = tid + i * 512;           // float4 index in 64x32 tile
        int r = lin >> 5, c4 = lin & 31;
        int gr = row0 + r;
        float4 v = make_float4(0.f, 0.f, 0.f, 0.f);
        if (gr < NN) v = ((const float4*)(Z + (size_t)gr * DD))[c4];
        if (doBn) {
            int c = c4 * 4;
            v.x = fmaxf(0.f, fmaf(v.x, AbnS[c + 0], BbnS[c + 0]));
            v.y = fmaxf(0.f, fmaf(v.y, AbnS[c + 1], BbnS[c + 1]));
            v.z = fmaxf(0.f, fmaf(v.z, AbnS[c + 2], BbnS[c + 2]));
            v.w = fmaxf(0.f, fmaf(v.w, AbnS[c + 3], BbnS[c + 3]));
        }
        Zs4[lin] = v;
    }
    __syncthreads();

    const int tx = tid & 31;   // 4 output cols: 4*tx..4*tx+3
    const int ty = tid >> 5;   // 4 output rows: 4*ty..4*ty+3
    float4 acc[4];
#pragma unroll
    for (int i = 0; i < 4; ++i) acc[i] = make_float4(0.f, 0.f, 0.f, 0.f);

    const float4* Wc = (const float4*)Ws;
    const float4* Zc = (const float4*)Zs;
#pragma unroll 4
    for (int k = 0; k < DD; k += 4) {
        float4 w0 = Wc[(k + 0) * 32 + tx];
        float4 w1 = Wc[(k + 1) * 32 + tx];
        float4 w2 = Wc[(k + 2) * 32 + tx];
        float4 w3 = Wc[(k + 3) * 32 + tx];
#pragma unroll
        for (int i = 0; i < 4; ++i) {
            float4 zv = Zc[(ty * 4 + i) * 32 + (k >> 2)];
            acc[i].x += zv.x * w0.x + zv.y * w1.x + zv.z * w2.x + zv.w * w3.x;
            acc[i].y += zv.x * w0.y + zv.y * w1.y + zv.z * w2.y + zv.w * w3.y;
            acc[i].z += zv.x * w0.z + zv.y * w1.z + zv.z * w2.z + zv.w * w3.z;
            acc[i].w += zv.x * w0.w + zv.y * w1.w + zv.z * w2.w + zv.w * w3.w;
        }
    }

    float4 bias4 = ((const float4*)bias)[tx];
    float4 s = make_float4(0.f, 0.f, 0.f, 0.f);
    float4 q = make_float4(0.f, 0.f, 0.f, 0.f);
#pragma unroll
    for (int i = 0; i < 4; ++i) {
        int gr = row0 + ty * 4 + i;
        if (gr < NN) {
            float4 o;
            o.x = acc[i].x + bias4.x;
            o.y = acc[i].y + bias4.y;
            o.z = acc[i].z + bias4.z;
            o.w = acc[i].w + bias4.w;
            ((float4*)Out)[(size_t)gr * 32 + tx] = o;
            s.x += o.x; s.y += o.y; s.z += o.z; s.w += o.w;
            q.x += o.x * o.x; q.y += o.y * o.y; q.z += o.z * o.z; q.w += o.w * o.w;
        }
    }

    if (statsOut) {
        __syncthreads();  // everyone done reading Zs
        float4* red = (float4*)Zs;
        red[tid] = s;
        red[512 + tid] = q;
        __syncthreads();
#pragma unroll
        for (int off = 256; off >= 32; off >>= 1) {
            if (tid < off) {
                red[tid].x += red[tid + off].x;
                red[tid].y += red[tid + off].y;
                red[tid].z += red[tid + off].z;
                red[tid].w += red[tid + off].w;
                red[512 + tid].x += red[512 + tid + off].x;
                red[512 + tid].y += red[512 + tid + off].y;
                red[512 + tid].z += red[512 + tid + off].z;
                red[512 + tid].w += red[512 + tid + off].w;
            }
            __syncthreads();
        }
        if (tid < 32) {
            float4 ts = red[tid], tq = red[512 + tid];
            atomicAdd(&statsOut[tid * 4 + 0], ts.x);
            atomicAdd(&statsOut[tid * 4 + 1], ts.y);
            atomicAdd(&statsOut[tid * 4 + 2], ts.z);
            atomicAdd(&statsOut[tid * 4 + 3], ts.w);
            atomicAdd(&statsOut[DD + tid * 4 + 0], tq.x);
            atomicAdd(&statsOut[DD + tid * 4 + 1], tq.y);
            atomicAdd(&statsOut[DD + tid * 4 + 2], tq.z);
            atomicAdd(&statsOut[DD + tid * 4 + 3], tq.w);
        }
    }
}

// ---------------- BN+ReLU apply + per-graph pooling (batch sorted -> contiguous rows) ----------------

__global__ __launch_bounds__(128) void apply_pool(const float* __restrict__ Z,
                                                  const float* __restrict__ stats,
                                                  const float* __restrict__ gamma,
                                                  const float* __restrict__ beta,
                                                  const int* __restrict__ gptr,
                                                  float* __restrict__ H,
                                                  float* __restrict__ pooledDst) {
    int g = blockIdx.x, c = threadIdx.x;
    float mu = stats[c] * (1.0f / NN);
    float var = stats[DD + c] * (1.0f / NN) - mu * mu;
    float A = gamma[c] * rsqrtf(var + BN_EPS);
    float B = beta[c] - mu * A;
    float acc = 0.f;
    int beg = gptr[g], end = gptr[g + 1];
    for (int r = beg; r < end; ++r) {
        float v = fmaxf(0.f, fmaf(Z[(size_t)r * DD + c], A, B));
        H[(size_t)r * DD + c] = v;
        acc += v;
    }
    pooledDst[(size_t)g * DD + c] = acc;
}

// plain pooling (for the raw input x)
__global__ __launch_bounds__(128) void pool_kernel(const float* __restrict__ src,
                                                   const int* __restrict__ gptr,
                                                   float* __restrict__ dst) {
    int g = blockIdx.x, d = threadIdx.x;
    float acc = 0.f;
    int beg = gptr[g], end = gptr[g + 1];
    for (int r = beg; r < end; ++r) acc += src[(size_t)r * DD + d];
    dst[(size_t)g * DD + d] = acc;
}

// ---------------- classifier + log_softmax ----------------

__global__ __launch_bounds__(64) void final_kernel(const float* __restrict__ pooled,
                                                   const float* __restrict__ fcW,
                                                   const float* __restrict__ fcb,
                                                   float* __restrict__ out) {
    int g = blockIdx.x;
    int lane = threadIdx.x;
    float acc[CC];
#pragma unroll
    for (int c = 0; c < CC; ++c) acc[c] = 0.f;
    for (int i = 0; i < LL + 1; ++i) {
        const float* P = pooled + ((size_t)i * GG + g) * DD;
        const float* Wf = fcW + (size_t)i * DD * CC;
        for (int k = lane; k < DD; k += 64) {
            float p = P[k];
            const float* wr = Wf + k * CC;
#pragma unroll
            for (int c = 0; c < CC; ++c) acc[c] = fmaf(p, wr[c], acc[c]);
        }
    }
#pragma unroll
    for (int c = 0; c < CC; ++c)
        for (int off = 32; off > 0; off >>= 1) acc[c] += __shfl_down(acc[c], off);
    if (lane == 0) {
#pragma unroll
        for (int c = 0; c < CC; ++c) {
            float b = 0.f;
            for (int i = 0; i < LL + 1; ++i) b += fcb[i * CC + c];
            acc[c] += b;
        }
        float m = acc[0];
#pragma unroll
        for (int c = 1; c < CC; ++c) m = fmaxf(m, acc[c]);
        float se = 0.f;
#pragma unroll
        for (int c = 0; c < CC; ++c) se += expf(acc[c] - m);
        float lse = m + logf(se);
#pragma unroll
        for (int c = 0; c < CC; ++c) out[(size_t)g * CC + c] = acc[c] - lse;
    }
}

// ---------------- launch ----------------

extern "C" void kernel_launch(void* const* d_in, const int* in_sizes, int n_in,
                              void* d_out, int out_size, void* d_ws, size_t ws_size,
                              hipStream_t stream) {
    const float* x     = (const float*)d_in[0];
    const int*   ei    = (const int*)d_in[1];
    const int*   batch = (const int*)d_in[2];
    const float* Wc1   = (const float*)d_in[3];
    const float* bc1   = (const float*)d_in[4];
    const float* Wc2   = (const float*)d_in[5];
    const float* bc2   = (const float*)d_in[6];
    const float* g_mid = (const float*)d_in[7];
    const float* b_mid = (const float*)d_in[8];
    const float* g_out = (const float*)d_in[9];
    const float* b_out = (const float*)d_in[10];
    const float* fcW   = (const float*)d_in[11];
    const float* fcb   = (const float*)d_in[12];
    float* out = (float*)d_out;

    char* p = (char*)d_ws;
    float* h      = (float*)p; p += (size_t)NN * DD * 4;
    float* bufA   = (float*)p; p += (size_t)NN * DD * 4;
    float* bufB   = (float*)p; p += (size_t)NN * DD * 4;
    float* pooled = (float*)p; p += (size_t)(LL + 1) * GG * DD * 4;
    float* statb  = (float*)p; p += 8 * 256 * 4;     // 8 stat blocks [sum|sumsq]
    int* deg    = (int*)p; p += (size_t)NN * 4;
    int* gcnt   = (int*)p; p += (size_t)GG * 4;
    int* rowptr = (int*)p; p += (size_t)(NN + 1) * 4;
    int* cursor = (int*)p; p += (size_t)NN * 4;
    int* csr    = (int*)p; p += (size_t)EE * 4;
    int* gptr   = (int*)p; p += (size_t)(GG + 1) * 4;

    // statb, deg, gcnt are contiguous: zero in one shot
    hipMemsetAsync(statb, 0, (size_t)(8 * 256 + NN + GG) * 4, stream);

    const int* src = ei;
    const int* dst = ei + EE;

    hist_kernel<<<(EE + 255) / 256, 256, 0, stream>>>(dst, deg, EE);
    scan_excl<<<1, 1024, 0, stream>>>(deg, rowptr, cursor, NN);
    fill_csr<<<(EE + 255) / 256, 256, 0, stream>>>(src, dst, cursor, csr);
    hist_kernel<<<(NN + 255) / 256, 256, 0, stream>>>(batch, gcnt, NN);
    scan_excl<<<1, 1024, 0, stream>>>(gcnt, gptr, nullptr, GG);
    pool_kernel<<<GG, 128, 0, stream>>>(x, gptr, pooled);

    const int gemmGrid = (NN + 63) / 64;  // 782
    const float* hin = x;
    for (int l = 0; l < LL; ++l) {
        aggregate<<<(NN + 3) / 4, 256, 0, stream>>>(hin, rowptr, csr, bufA);
        gemm_kernel<<<gemmGrid, 512, 0, stream>>>(
            bufA, Wc1 + (size_t)l * DD * DD, bc1 + (size_t)l * DD,
            nullptr, nullptr, nullptr,
            bufB, statb + (size_t)(2 * l) * 256);
        gemm_kernel<<<gemmGrid, 512, 0, stream>>>(
            bufB, Wc2 + (size_t)l * DD * DD, bc2 + (size_t)l * DD,
            statb + (size_t)(2 * l) * 256, g_mid + (size_t)l * DD, b_mid + (size_t)l * DD,
            bufA, statb + (size_t)(2 * l + 1) * 256);
        apply_pool<<<GG, 128, 0, stream>>>(
            bufA, statb + (size_t)(2 * l + 1) * 256, g_out + (size_t)l * DD, b_out + (size_t)l * DD,
            gptr, h, pooled + (size_t)(l + 1) * GG * DD);
        hin = h;
    }
    final_kernel<<<GG, 64, 0, stream>>>(pooled, fcW, fcb, out);
}

// Round 2
// 680.465 us; speedup vs baseline: 2.1333x; 2.1333x over previous
//
#include <hip/hip_runtime.h>
#include <hip/hip_bf16.h>

#define NN 50000
#define EE 600000
#define DD 128
#define LL 4
#define CC 10
#define GG 512
#define BN_EPS 1e-5f

typedef __attribute__((ext_vector_type(8))) short short8;
typedef __attribute__((ext_vector_type(4))) float f32x4;

__device__ __forceinline__ unsigned short f2b(float f) {
    union { float f; unsigned int u; } v; v.f = f;
    unsigned int u = v.u;
    unsigned int r = (u + 0x7fffu + ((u >> 16) & 1u)) >> 16;
    return (unsigned short)r;
}
__device__ __forceinline__ float b2f(unsigned short h) {
    union { unsigned int u; float f; } v; v.u = ((unsigned int)h) << 16;
    return v.f;
}

// ---------------- conversions ----------------

__global__ __launch_bounds__(256) void cvt_bf16(const float* __restrict__ in,
                                                unsigned short* __restrict__ out) {
    int i = blockIdx.x * 256 + threadIdx.x;      // one float2 per thread
    float2 v = ((const float2*)in)[i];
    unsigned int o = (unsigned int)f2b(v.x) | ((unsigned int)f2b(v.y) << 16);
    ((unsigned int*)out)[i] = o;
}

// WTb[mat][n][k] = W[mat][k][n], bf16.  mats 0..3 = Wc1, 4..7 = Wc2
__global__ __launch_bounds__(256) void prep_weights(const float* __restrict__ Wc1,
                                                    const float* __restrict__ Wc2,
                                                    unsigned short* __restrict__ WTb) {
    int idx = blockIdx.x * 256 + threadIdx.x;    // 131072 total
    int mat = idx >> 14;
    int n = (idx >> 7) & 127;
    int k = idx & 127;
    const float* srcp = (mat < 4) ? (Wc1 + (size_t)mat * DD * DD)
                                  : (Wc2 + (size_t)(mat - 4) * DD * DD);
    WTb[idx] = f2b(srcp[k * DD + n]);
    (void)n;
}

// ---------------- CSR build ----------------

__global__ void hist_kernel(const int* __restrict__ idx, int* __restrict__ cnt, int n) {
    int i = blockIdx.x * blockDim.x + threadIdx.x;
    if (i < n) atomicAdd(&cnt[idx[i]], 1);
}

// hierarchical scan: 1024 elems per block, 256 threads x 4
__global__ __launch_bounds__(256) void block_sums(const int* __restrict__ in,
                                                  int* __restrict__ bsums, int n) {
    __shared__ int red[256];
    int b = blockIdx.x, t = threadIdx.x;
    int base = b * 1024 + t * 4;
    int s = 0;
    if (base + 3 < n) {
        int4 v = *(const int4*)(in + base);
        s = v.x + v.y + v.z + v.w;
    } else {
        for (int i = 0; i < 4; ++i) if (base + i < n) s += in[base + i];
    }
    red[t] = s;
    __syncthreads();
    for (int off = 128; off > 0; off >>= 1) {
        if (t < off) red[t] += red[t + off];
        __syncthreads();
    }
    if (t == 0) bsums[b] = red[0];
}

// single block, nb <= 256: exclusive scan in place, bsums[nb] = total
__global__ __launch_bounds__(256) void scan_bsums(int* __restrict__ bsums, int nb) {
    __shared__ int red[256];
    int t = threadIdx.x;
    int v = (t < nb) ? bsums[t] : 0;
    red[t] = v;
    __syncthreads();
    for (int off = 1; off < 256; off <<= 1) {
        int u = (t >= off) ? red[t - off] : 0;
        __syncthreads();
        red[t] += u;
        __syncthreads();
    }
    if (t < nb) bsums[t] = red[t] - v;
    if (t == 0) bsums[nb] = red[255];
}

__global__ __launch_bounds__(256) void scan_final(const int* __restrict__ in,
                                                  const int* __restrict__ bsums,
                                                  int* __restrict__ out,
                                                  int* __restrict__ out2, int n) {
    __shared__ int red[256];
    int b = blockIdx.x, t = threadIdx.x;
    int base = b * 1024 + t * 4;
    int v[4];
    int s = 0;
#pragma unroll
    for (int i = 0; i < 4; ++i) {
        v[i] = (base + i < n) ? in[base + i] : 0;
        s += v[i];
    }
    red[t] = s;
    __syncthreads();
    for (int off = 1; off < 256; off <<= 1) {
        int u = (t >= off) ? red[t - off] : 0;
        __syncthreads();
        red[t] += u;
        __syncthreads();
    }
    int run = bsums[b] + red[t] - s;
#pragma unroll
    for (int i = 0; i < 4; ++i) {
        if (base + i < n) {
            out[base + i] = run;
            if (out2) out2[base + i] = run;
            run += v[i];
        }
    }
    if (b == (int)gridDim.x - 1 && t == 255) out[n] = run;  // total
}

__global__ void fill_csr(const int* __restrict__ src, const int* __restrict__ dst,
                         int* __restrict__ cursor, int* __restrict__ csr) {
    int e = blockIdx.x * blockDim.x + threadIdx.x;
    if (e < EE) {
        int d = dst[e];
        int pos = atomicAdd(&cursor[d], 1);
        csr[pos] = src[e];
    }
}

// gptr via binary search on sorted batch
__global__ void gptr_search(const int* __restrict__ batch, int* __restrict__ gptr) {
    int g = blockIdx.x * blockDim.x + threadIdx.x;
    if (g > GG) return;
    int lo = 0, hi = NN;
    while (lo < hi) {
        int mid = (lo + hi) >> 1;
        if (batch[mid] < g) lo = mid + 1; else hi = mid;
    }
    gptr[g] = lo;
}

// ---------------- aggregation (bf16 in/out, f32 accumulate) ----------------

__global__ __launch_bounds__(256) void aggregate_bf16(const unsigned short* __restrict__ hb,
                                                      const int* __restrict__ rowptr,
                                                      const int* __restrict__ csr,
                                                      unsigned short* __restrict__ outb) {
    int node = blockIdx.x * 4 + (threadIdx.x >> 6);  // one wave per node
    if (node >= NN) return;
    int lane = threadIdx.x & 63;
    unsigned int u = ((const unsigned int*)(hb + (size_t)node * DD))[lane];
    float ax = b2f((unsigned short)(u & 0xffff));
    float ay = b2f((unsigned short)(u >> 16));
    int beg = rowptr[node], end = rowptr[node + 1];
    for (int e = beg; e < end; ++e) {
        int s = csr[e];
        unsigned int v = ((const unsigned int*)(hb + (size_t)s * DD))[lane];
        ax += b2f((unsigned short)(v & 0xffff));
        ay += b2f((unsigned short)(v >> 16));
    }
    unsigned int o = (unsigned int)f2b(ax) | ((unsigned int)f2b(ay) << 16);
    ((unsigned int*)(outb + (size_t)node * DD))[lane] = o;
}

// ---------------- MFMA GEMM: Out = (bn?)(Z) @ W + bias, + column stats ----------------
// A = Z tile [128 rows x 128 k] bf16 (row-major), B = WT [128 n x 128 k] bf16.
// 4 waves: wave w owns rows [w*32, w*32+32): acc[2][8] 16x16 fragments.

__global__ __launch_bounds__(256) void gemm_mfma(
    const unsigned short* __restrict__ Ab,   // [NN][128] bf16
    const unsigned short* __restrict__ WTb,  // [128][128] bf16 (WT[n][k])
    const float* __restrict__ bias,
    const float* __restrict__ bnStatsIn,     // null => raw input
    const float* __restrict__ gamma, const float* __restrict__ beta,
    unsigned short* __restrict__ Outb,       // [NN][128] bf16
    float* __restrict__ statsOut)            // [0..127]=colsum, [128..255]=colsumsq
{
    __shared__ unsigned short As[128 * 128];  // 32 KB, XOR-swizzled rows
    __shared__ unsigned short Bs[128 * 128];  // 32 KB
    __shared__ float AbnS[DD], BbnS[DD];
    __shared__ float colred[2][DD];

    const int tid = threadIdx.x;
    const int row0 = blockIdx.x * 128;
    const bool doBn = (bnStatsIn != nullptr);

    if (tid < DD) {
        colred[0][tid] = 0.f;
        colred[1][tid] = 0.f;
        if (doBn) {
            float mu = bnStatsIn[tid] * (1.0f / NN);
            float var = bnStatsIn[DD + tid] * (1.0f / NN) - mu * mu;
            float A = gamma[tid] * rsqrtf(var + BN_EPS);
            AbnS[tid] = A;
            BbnS[tid] = beta[tid] - mu * A;
        }
    }
    __syncthreads();

    // stage B (weights): 2048 16B-chunks
    const uint4* Bg = (const uint4*)WTb;
#pragma unroll
    for (int i = 0; i < 8; ++i) {
        int c = tid + i * 256;
        int row = c >> 4, seg = c & 15;
        uint4 v = Bg[c];
        int byte = (row * 256 + seg * 16) ^ ((row & 7) << 4);
        *(uint4*)((char*)Bs + byte) = v;
    }
    // stage A (activations), optional BN+ReLU on load
#pragma unroll
    for (int i = 0; i < 8; ++i) {
        int c = tid + i * 256;
        int row = c >> 4, seg = c & 15;
        int gr = row0 + row;
        uint4 v = make_uint4(0u, 0u, 0u, 0u);
        if (gr < NN) v = ((const uint4*)(Ab + (size_t)gr * DD))[seg];
        if (doBn) {
            int k0 = seg * 8;
#pragma unroll
            for (int e = 0; e < 4; ++e) {
                unsigned int u = ((unsigned int*)&v)[e];
                int cidx = k0 + 2 * e;
                float lo = fmaxf(0.f, fmaf(b2f((unsigned short)(u & 0xffff)), AbnS[cidx], BbnS[cidx]));
                float hi = fmaxf(0.f, fmaf(b2f((unsigned short)(u >> 16)), AbnS[cidx + 1], BbnS[cidx + 1]));
                ((unsigned int*)&v)[e] = (unsigned int)f2b(lo) | ((unsigned int)f2b(hi) << 16);
            }
        }
        int byte = (row * 256 + seg * 16) ^ ((row & 7) << 4);
        *(uint4*)((char*)As + byte) = v;
    }
    __syncthreads();

    const int wave = tid >> 6, lane = tid & 63;
    const int fr = lane & 15, fq = lane >> 4;
    const int wr0 = wave * 32;

    f32x4 acc[2][8];
#pragma unroll
    for (int m = 0; m < 2; ++m)
#pragma unroll
        for (int n = 0; n < 8; ++n) acc[m][n] = (f32x4)0.f;

#pragma unroll
    for (int kk = 0; kk < 4; ++kk) {
        int kbyte = kk * 64 + fq * 16;
        short8 a[2], b[8];
#pragma unroll
        for (int m = 0; m < 2; ++m) {
            int row = wr0 + m * 16 + fr;
            a[m] = *(const short8*)((const char*)As + ((row * 256 + kbyte) ^ ((row & 7) << 4)));
        }
#pragma unroll
        for (int n = 0; n < 8; ++n) {
            int row = n * 16 + fr;
            b[n] = *(const short8*)((const char*)Bs + ((row * 256 + kbyte) ^ ((row & 7) << 4)));
        }
#pragma unroll
        for (int m = 0; m < 2; ++m)
#pragma unroll
            for (int n = 0; n < 8; ++n)
                acc[m][n] = __builtin_amdgcn_mfma_f32_16x16x32_bf16(a[m], b[n], acc[m][n], 0, 0, 0);
    }

    // epilogue: bias, bf16 store, column stats
    float bias_n[8], s[8], q[8];
#pragma unroll
    for (int n = 0; n < 8; ++n) {
        bias_n[n] = bias[n * 16 + fr];
        s[n] = 0.f;
        q[n] = 0.f;
    }
#pragma unroll
    for (int m = 0; m < 2; ++m) {
        int rbase = row0 + wr0 + m * 16 + fq * 4;
#pragma unroll
        for (int j = 0; j < 4; ++j) {
            int gr = rbase + j;
            if (gr < NN) {
#pragma unroll
                for (int n = 0; n < 8; ++n) {
                    float o = acc[m][n][j] + bias_n[n];
                    Outb[(size_t)gr * DD + n * 16 + fr] = f2b(o);
                    s[n] += o;
                    q[n] += o * o;
                }
            }
        }
    }
    if (statsOut) {
#pragma unroll
        for (int n = 0; n < 8; ++n) {
            s[n] += __shfl_xor(s[n], 16);
            s[n] += __shfl_xor(s[n], 32);
            q[n] += __shfl_xor(q[n], 16);
            q[n] += __shfl_xor(q[n], 32);
        }
        if (fq == 0) {
#pragma unroll
            for (int n = 0; n < 8; ++n) {
                atomicAdd(&colred[0][n * 16 + fr], s[n]);
                atomicAdd(&colred[1][n * 16 + fr], q[n]);
            }
        }
        __syncthreads();
        if (tid < DD) {
            atomicAdd(&statsOut[tid], colred[0][tid]);
            atomicAdd(&statsOut[DD + tid], colred[1][tid]);
        }
    }
}

// ---------------- BN+ReLU apply + per-graph pooling ----------------

__global__ __launch_bounds__(128) void apply_pool(const unsigned short* __restrict__ Z,
                                                  const float* __restrict__ stats,
                                                  const float* __restrict__ gamma,
                                                  const float* __restrict__ beta,
                                                  const int* __restrict__ gptr,
                                                  unsigned short* __restrict__ H,
                                                  float* __restrict__ pooledDst) {
    int g = blockIdx.x, c = threadIdx.x;
    float mu = stats[c] * (1.0f / NN);
    float var = stats[DD + c] * (1.0f / NN) - mu * mu;
    float A = gamma[c] * rsqrtf(var + BN_EPS);
    float B = beta[c] - mu * A;
    float acc = 0.f;
    int beg = gptr[g], end = gptr[g + 1];
    for (int r = beg; r < end; ++r) {
        float v = fmaxf(0.f, fmaf(b2f(Z[(size_t)r * DD + c]), A, B));
        H[(size_t)r * DD + c] = f2b(v);
        acc += v;
    }
    pooledDst[(size_t)g * DD + c] = acc;
}

// plain pooling of raw f32 x
__global__ __launch_bounds__(128) void pool_kernel(const float* __restrict__ src,
                                                   const int* __restrict__ gptr,
                                                   float* __restrict__ dst) {
    int g = blockIdx.x, d = threadIdx.x;
    float acc = 0.f;
    int beg = gptr[g], end = gptr[g + 1];
    for (int r = beg; r < end; ++r) acc += src[(size_t)r * DD + d];
    dst[(size_t)g * DD + d] = acc;
}

// ---------------- classifier + log_softmax ----------------

__global__ __launch_bounds__(64) void final_kernel(const float* __restrict__ pooled,
                                                   const float* __restrict__ fcW,
                                                   const float* __restrict__ fcb,
                                                   float* __restrict__ out) {
    int g = blockIdx.x;
    int lane = threadIdx.x;
    float acc[CC];
#pragma unroll
    for (int c = 0; c < CC; ++c) acc[c] = 0.f;
    for (int i = 0; i < LL + 1; ++i) {
        const float* P = pooled + ((size_t)i * GG + g) * DD;
        const float* Wf = fcW + (size_t)i * DD * CC;
        for (int k = lane; k < DD; k += 64) {
            float p = P[k];
            const float* wr = Wf + k * CC;
#pragma unroll
            for (int c = 0; c < CC; ++c) acc[c] = fmaf(p, wr[c], acc[c]);
        }
    }
#pragma unroll
    for (int c = 0; c < CC; ++c)
        for (int off = 32; off > 0; off >>= 1) acc[c] += __shfl_down(acc[c], off);
    if (lane == 0) {
#pragma unroll
        for (int c = 0; c < CC; ++c) {
            float b = 0.f;
            for (int i = 0; i < LL + 1; ++i) b += fcb[i * CC + c];
            acc[c] += b;
        }
        float m = acc[0];
#pragma unroll
        for (int c = 1; c < CC; ++c) m = fmaxf(m, acc[c]);
        float se = 0.f;
#pragma unroll
        for (int c = 0; c < CC; ++c) se += expf(acc[c] - m);
        float lse = m + logf(se);
#pragma unroll
        for (int c = 0; c < CC; ++c) out[(size_t)g * CC + c] = acc[c] - lse;
    }
}

// ---------------- launch ----------------

extern "C" void kernel_launch(void* const* d_in, const int* in_sizes, int n_in,
                              void* d_out, int out_size, void* d_ws, size_t ws_size,
                              hipStream_t stream) {
    const float* x     = (const float*)d_in[0];
    const int*   ei    = (const int*)d_in[1];
    const int*   batch = (const int*)d_in[2];
    const float* Wc1   = (const float*)d_in[3];
    const float* bc1   = (const float*)d_in[4];
    const float* Wc2   = (const float*)d_in[5];
    const float* bc2   = (const float*)d_in[6];
    const float* g_mid = (const float*)d_in[7];
    const float* b_mid = (const float*)d_in[8];
    const float* g_out = (const float*)d_in[9];
    const float* b_out = (const float*)d_in[10];
    const float* fcW   = (const float*)d_in[11];
    const float* fcb   = (const float*)d_in[12];
    float* out = (float*)d_out;

    char* p = (char*)d_ws;
    unsigned short* xb   = (unsigned short*)p; p += (size_t)NN * DD * 2;
    unsigned short* hb   = (unsigned short*)p; p += (size_t)NN * DD * 2;
    unsigned short* aggb = (unsigned short*)p; p += (size_t)NN * DD * 2;
    unsigned short* z1b  = (unsigned short*)p; p += (size_t)NN * DD * 2;
    unsigned short* WTb  = (unsigned short*)p; p += (size_t)8 * DD * DD * 2;
    float* pooled = (float*)p; p += (size_t)(LL + 1) * GG * DD * 4;
    float* statb  = (float*)p; p += 8 * 256 * 4;
    int* deg    = (int*)p; p += (size_t)NN * 4;       // right after statb (joint memset)
    int* rowptr = (int*)p; p += (size_t)(NN + 16) * 4;
    int* cursor = (int*)p; p += (size_t)NN * 4;
    int* csr    = (int*)p; p += (size_t)EE * 4;
    int* gptr   = (int*)p; p += (size_t)(GG + 16) * 4;
    int* bsum1  = (int*)p; p += 64 * 4;

    // zero stats + degree histogram in one shot (contiguous)
    hipMemsetAsync(statb, 0, (size_t)(8 * 256) * 4 + (size_t)NN * 4, stream);

    const int* src = ei;
    const int* dst = ei + EE;

    cvt_bf16<<<(NN * DD / 2) / 256, 256, 0, stream>>>(x, xb);
    prep_weights<<<(8 * DD * DD) / 256, 256, 0, stream>>>(Wc1, Wc2, WTb);

    hist_kernel<<<(EE + 255) / 256, 256, 0, stream>>>(dst, deg, EE);
    const int nb = (NN + 1023) / 1024;  // 49
    block_sums<<<nb, 256, 0, stream>>>(deg, bsum1, NN);
    scan_bsums<<<1, 256, 0, stream>>>(bsum1, nb);
    scan_final<<<nb, 256, 0, stream>>>(deg, bsum1, rowptr, cursor, NN);
    fill_csr<<<(EE + 255) / 256, 256, 0, stream>>>(src, dst, cursor, csr);
    gptr_search<<<3, 256, 0, stream>>>(batch, gptr);
    pool_kernel<<<GG, 128, 0, stream>>>(x, gptr, pooled);

    const int gemmGrid = (NN + 127) / 128;  // 391
    const unsigned short* hin = xb;
    for (int l = 0; l < LL; ++l) {
        aggregate_bf16<<<(NN + 3) / 4, 256, 0, stream>>>(hin, rowptr, csr, aggb);
        gemm_mfma<<<gemmGrid, 256, 0, stream>>>(
            aggb, WTb + (size_t)l * DD * DD, bc1 + (size_t)l * DD,
            nullptr, nullptr, nullptr,
            z1b, statb + (size_t)(2 * l) * 256);
        gemm_mfma<<<gemmGrid, 256, 0, stream>>>(
            z1b, WTb + (size_t)(4 + l) * DD * DD, bc2 + (size_t)l * DD,
            statb + (size_t)(2 * l) * 256, g_mid + (size_t)l * DD, b_mid + (size_t)l * DD,
            aggb, statb + (size_t)(2 * l + 1) * 256);
        apply_pool<<<GG, 128, 0, stream>>>(
            aggb, statb + (size_t)(2 * l + 1) * 256, g_out + (size_t)l * DD, b_out + (size_t)l * DD,
            gptr, hb, pooled + (size_t)(l + 1) * GG * DD);
        hin = hb;
    }
    final_kernel<<<GG, 64, 0, stream>>>(pooled, fcW, fcb, out);
}

// Round 3
// 430.326 us; speedup vs baseline: 3.3733x; 1.5813x over previous
//
#include <hip/hip_runtime.h>
#include <hip/hip_bf16.h>

#define NN 50000
#define EE 600000
#define DD 128
#define LL 4
#define CC 10
#define GG 512
#define BN_EPS 1e-5f

typedef __attribute__((ext_vector_type(8))) short short8;
typedef __attribute__((ext_vector_type(4))) float f32x4;

__device__ __forceinline__ unsigned short f2b(float f) {
    union { float f; unsigned int u; } v; v.f = f;
    unsigned int u = v.u;
    unsigned int r = (u + 0x7fffu + ((u >> 16) & 1u)) >> 16;
    return (unsigned short)r;
}
__device__ __forceinline__ float b2f(unsigned short h) {
    union { unsigned int u; float f; } v; v.u = ((unsigned int)h) << 16;
    return v.f;
}

// ---------------- conversions ----------------

__global__ __launch_bounds__(256) void cvt_bf16(const float* __restrict__ in,
                                                unsigned short* __restrict__ out) {
    int i = blockIdx.x * 256 + threadIdx.x;      // one float2 per thread
    float2 v = ((const float2*)in)[i];
    unsigned int o = (unsigned int)f2b(v.x) | ((unsigned int)f2b(v.y) << 16);
    ((unsigned int*)out)[i] = o;
}

// WTb[mat][n][k] = W[mat][k][n], bf16.  mats 0..3 = Wc1, 4..7 = Wc2
__global__ __launch_bounds__(256) void prep_weights(const float* __restrict__ Wc1,
                                                    const float* __restrict__ Wc2,
                                                    unsigned short* __restrict__ WTb) {
    int idx = blockIdx.x * 256 + threadIdx.x;    // 131072 total
    int mat = idx >> 14;
    int n = (idx >> 7) & 127;
    int k = idx & 127;
    const float* srcp = (mat < 4) ? (Wc1 + (size_t)mat * DD * DD)
                                  : (Wc2 + (size_t)(mat - 4) * DD * DD);
    WTb[idx] = f2b(srcp[k * DD + n]);
}

// ---------------- CSR build ----------------

__global__ void hist_kernel(const int* __restrict__ idx, int* __restrict__ cnt, int n) {
    int i = blockIdx.x * blockDim.x + threadIdx.x;
    if (i < n) atomicAdd(&cnt[idx[i]], 1);
}

__global__ __launch_bounds__(256) void block_sums(const int* __restrict__ in,
                                                  int* __restrict__ bsums, int n) {
    __shared__ int red[256];
    int b = blockIdx.x, t = threadIdx.x;
    int base = b * 1024 + t * 4;
    int s = 0;
    if (base + 3 < n) {
        int4 v = *(const int4*)(in + base);
        s = v.x + v.y + v.z + v.w;
    } else {
        for (int i = 0; i < 4; ++i) if (base + i < n) s += in[base + i];
    }
    red[t] = s;
    __syncthreads();
    for (int off = 128; off > 0; off >>= 1) {
        if (t < off) red[t] += red[t + off];
        __syncthreads();
    }
    if (t == 0) bsums[b] = red[0];
}

__global__ __launch_bounds__(256) void scan_bsums(int* __restrict__ bsums, int nb) {
    __shared__ int red[256];
    int t = threadIdx.x;
    int v = (t < nb) ? bsums[t] : 0;
    red[t] = v;
    __syncthreads();
    for (int off = 1; off < 256; off <<= 1) {
        int u = (t >= off) ? red[t - off] : 0;
        __syncthreads();
        red[t] += u;
        __syncthreads();
    }
    if (t < nb) bsums[t] = red[t] - v;
    if (t == 0) bsums[nb] = red[255];
}

__global__ __launch_bounds__(256) void scan_final(const int* __restrict__ in,
                                                  const int* __restrict__ bsums,
                                                  int* __restrict__ out,
                                                  int* __restrict__ out2, int n) {
    __shared__ int red[256];
    int b = blockIdx.x, t = threadIdx.x;
    int base = b * 1024 + t * 4;
    int v[4];
    int s = 0;
#pragma unroll
    for (int i = 0; i < 4; ++i) {
        v[i] = (base + i < n) ? in[base + i] : 0;
        s += v[i];
    }
    red[t] = s;
    __syncthreads();
    for (int off = 1; off < 256; off <<= 1) {
        int u = (t >= off) ? red[t - off] : 0;
        __syncthreads();
        red[t] += u;
        __syncthreads();
    }
    int run = bsums[b] + red[t] - s;
#pragma unroll
    for (int i = 0; i < 4; ++i) {
        if (base + i < n) {
            out[base + i] = run;
            if (out2) out2[base + i] = run;
            run += v[i];
        }
    }
    if (b == (int)gridDim.x - 1 && t == 255) out[n] = run;
}

__global__ void fill_csr(const int* __restrict__ src, const int* __restrict__ dst,
                         int* __restrict__ cursor, int* __restrict__ csr) {
    int e = blockIdx.x * blockDim.x + threadIdx.x;
    if (e < EE) {
        int d = dst[e];
        int pos = atomicAdd(&cursor[d], 1);
        csr[pos] = src[e];
    }
}

__global__ void gptr_search(const int* __restrict__ batch, int* __restrict__ gptr) {
    int g = blockIdx.x * blockDim.x + threadIdx.x;
    if (g > GG) return;
    int lo = 0, hi = NN;
    while (lo < hi) {
        int mid = (lo + hi) >> 1;
        if (batch[mid] < g) lo = mid + 1; else hi = mid;
    }
    gptr[g] = lo;
}

// ---------------- aggregation with optional fused BN+ReLU on load ----------------
// out[n] = t(h[n]) + sum_{src} t(h[src]),  t = BN-affine+ReLU if BN else identity.
// One wave per node, 8-deep edge batching for load ILP.

template <bool BN>
__global__ __launch_bounds__(256) void aggregate_k(const unsigned short* __restrict__ hb,
                                                   const int* __restrict__ rowptr,
                                                   const int* __restrict__ csr,
                                                   const float* __restrict__ stats,
                                                   const float* __restrict__ gamma,
                                                   const float* __restrict__ beta,
                                                   unsigned short* __restrict__ outb) {
    int node = blockIdx.x * 4 + (threadIdx.x >> 6);
    if (node >= NN) return;
    int lane = threadIdx.x & 63;
    float A0 = 0.f, B0 = 0.f, A1 = 0.f, B1 = 0.f;
    if (BN) {
        int c0 = lane * 2, c1 = c0 + 1;
        float mu0 = stats[c0] * (1.0f / NN);
        float var0 = stats[DD + c0] * (1.0f / NN) - mu0 * mu0;
        A0 = gamma[c0] * rsqrtf(var0 + BN_EPS);
        B0 = beta[c0] - mu0 * A0;
        float mu1 = stats[c1] * (1.0f / NN);
        float var1 = stats[DD + c1] * (1.0f / NN) - mu1 * mu1;
        A1 = gamma[c1] * rsqrtf(var1 + BN_EPS);
        B1 = beta[c1] - mu1 * A1;
    }

    float ax, ay;
    {
        unsigned int u = ((const unsigned int*)(hb + (size_t)node * DD))[lane];
        float x = b2f((unsigned short)(u & 0xffff));
        float y = b2f((unsigned short)(u >> 16));
        if (BN) {
            x = fmaxf(0.f, fmaf(x, A0, B0));
            y = fmaxf(0.f, fmaf(y, A1, B1));
        }
        ax = x; ay = y;
    }

    int beg = rowptr[node], end = rowptr[node + 1];
    for (int e = beg; e < end; e += 8) {
        int m = end - e;                 // >=1
        int s[8];
#pragma unroll
        for (int i = 0; i < 8; ++i) s[i] = csr[e + ((i < m) ? i : 0)];
        unsigned int v[8];
#pragma unroll
        for (int i = 0; i < 8; ++i)
            v[i] = ((const unsigned int*)(hb + (size_t)s[i] * DD))[lane];
#pragma unroll
        for (int i = 0; i < 8; ++i) {
            if (i < m) {
                float x = b2f((unsigned short)(v[i] & 0xffff));
                float y = b2f((unsigned short)(v[i] >> 16));
                if (BN) {
                    x = fmaxf(0.f, fmaf(x, A0, B0));
                    y = fmaxf(0.f, fmaf(y, A1, B1));
                }
                ax += x; ay += y;
            }
        }
    }
    unsigned int o = (unsigned int)f2b(ax) | ((unsigned int)f2b(ay) << 16);
    ((unsigned int*)(outb + (size_t)node * DD))[lane] = o;
}

// ---------------- MFMA GEMM: Out = (bn?)(Z) @ W + bias, + column stats ----------------

__global__ __launch_bounds__(256) void gemm_mfma(
    const unsigned short* __restrict__ Ab,   // [NN][128] bf16
    const unsigned short* __restrict__ WTb,  // [128][128] bf16 (WT[n][k])
    const float* __restrict__ bias,
    const float* __restrict__ bnStatsIn,     // null => raw input
    const float* __restrict__ gamma, const float* __restrict__ beta,
    unsigned short* __restrict__ Outb,       // [NN][128] bf16
    float* __restrict__ statsOut)            // [0..127]=colsum, [128..255]=colsumsq
{
    __shared__ unsigned short As[128 * 128];
    __shared__ unsigned short Bs[128 * 128];
    __shared__ float AbnS[DD], BbnS[DD];
    __shared__ float colred[2][DD];

    const int tid = threadIdx.x;
    const int row0 = blockIdx.x * 128;
    const bool doBn = (bnStatsIn != nullptr);

    if (tid < DD) {
        colred[0][tid] = 0.f;
        colred[1][tid] = 0.f;
        if (doBn) {
            float mu = bnStatsIn[tid] * (1.0f / NN);
            float var = bnStatsIn[DD + tid] * (1.0f / NN) - mu * mu;
            float A = gamma[tid] * rsqrtf(var + BN_EPS);
            AbnS[tid] = A;
            BbnS[tid] = beta[tid] - mu * A;
        }
    }
    __syncthreads();

    const uint4* Bg = (const uint4*)WTb;
#pragma unroll
    for (int i = 0; i < 8; ++i) {
        int c = tid + i * 256;
        int row = c >> 4, seg = c & 15;
        uint4 v = Bg[c];
        int byte = (row * 256 + seg * 16) ^ ((row & 7) << 4);
        *(uint4*)((char*)Bs + byte) = v;
    }
#pragma unroll
    for (int i = 0; i < 8; ++i) {
        int c = tid + i * 256;
        int row = c >> 4, seg = c & 15;
        int gr = row0 + row;
        uint4 v = make_uint4(0u, 0u, 0u, 0u);
        if (gr < NN) v = ((const uint4*)(Ab + (size_t)gr * DD))[seg];
        if (doBn) {
            int k0 = seg * 8;
#pragma unroll
            for (int e = 0; e < 4; ++e) {
                unsigned int u = ((unsigned int*)&v)[e];
                int cidx = k0 + 2 * e;
                float lo = fmaxf(0.f, fmaf(b2f((unsigned short)(u & 0xffff)), AbnS[cidx], BbnS[cidx]));
                float hi = fmaxf(0.f, fmaf(b2f((unsigned short)(u >> 16)), AbnS[cidx + 1], BbnS[cidx + 1]));
                ((unsigned int*)&v)[e] = (unsigned int)f2b(lo) | ((unsigned int)f2b(hi) << 16);
            }
        }
        int byte = (row * 256 + seg * 16) ^ ((row & 7) << 4);
        *(uint4*)((char*)As + byte) = v;
    }
    __syncthreads();

    const int wave = tid >> 6, lane = tid & 63;
    const int fr = lane & 15, fq = lane >> 4;
    const int wr0 = wave * 32;

    f32x4 acc[2][8];
#pragma unroll
    for (int m = 0; m < 2; ++m)
#pragma unroll
        for (int n = 0; n < 8; ++n) acc[m][n] = (f32x4)0.f;

#pragma unroll
    for (int kk = 0; kk < 4; ++kk) {
        int kbyte = kk * 64 + fq * 16;
        short8 a[2], b[8];
#pragma unroll
        for (int m = 0; m < 2; ++m) {
            int row = wr0 + m * 16 + fr;
            a[m] = *(const short8*)((const char*)As + ((row * 256 + kbyte) ^ ((row & 7) << 4)));
        }
#pragma unroll
        for (int n = 0; n < 8; ++n) {
            int row = n * 16 + fr;
            b[n] = *(const short8*)((const char*)Bs + ((row * 256 + kbyte) ^ ((row & 7) << 4)));
        }
#pragma unroll
        for (int m = 0; m < 2; ++m)
#pragma unroll
            for (int n = 0; n < 8; ++n)
                acc[m][n] = __builtin_amdgcn_mfma_f32_16x16x32_bf16(a[m], b[n], acc[m][n], 0, 0, 0);
    }

    float bias_n[8], s[8], q[8];
#pragma unroll
    for (int n = 0; n < 8; ++n) {
        bias_n[n] = bias[n * 16 + fr];
        s[n] = 0.f;
        q[n] = 0.f;
    }
#pragma unroll
    for (int m = 0; m < 2; ++m) {
        int rbase = row0 + wr0 + m * 16 + fq * 4;
#pragma unroll
        for (int j = 0; j < 4; ++j) {
            int gr = rbase + j;
            if (gr < NN) {
#pragma unroll
                for (int n = 0; n < 8; ++n) {
                    float o = acc[m][n][j] + bias_n[n];
                    Outb[(size_t)gr * DD + n * 16 + fr] = f2b(o);
                    s[n] += o;
                    q[n] += o * o;
                }
            }
        }
    }
    if (statsOut) {
#pragma unroll
        for (int n = 0; n < 8; ++n) {
            s[n] += __shfl_xor(s[n], 16);
            s[n] += __shfl_xor(s[n], 32);
            q[n] += __shfl_xor(q[n], 16);
            q[n] += __shfl_xor(q[n], 32);
        }
        if (fq == 0) {
#pragma unroll
            for (int n = 0; n < 8; ++n) {
                atomicAdd(&colred[0][n * 16 + fr], s[n]);
                atomicAdd(&colred[1][n * 16 + fr], q[n]);
            }
        }
        __syncthreads();
        if (tid < DD) {
            atomicAdd(&statsOut[tid], colred[0][tid]);
            atomicAdd(&statsOut[DD + tid], colred[1][tid]);
        }
    }
}

// ---------------- pooled[g] = sum_{rows of g} relu(bn(Z[r])) ----------------

__global__ __launch_bounds__(256) void bn_pool(const unsigned short* __restrict__ Z,
                                               const float* __restrict__ stats,
                                               const float* __restrict__ gamma,
                                               const float* __restrict__ beta,
                                               const int* __restrict__ gptr,
                                               float* __restrict__ pooledDst) {
    __shared__ float2 red[4][64];
    int g = blockIdx.x;
    int wave = threadIdx.x >> 6, lane = threadIdx.x & 63;
    int c0 = lane * 2, c1 = c0 + 1;
    float mu0 = stats[c0] * (1.0f / NN);
    float var0 = stats[DD + c0] * (1.0f / NN) - mu0 * mu0;
    float A0 = gamma[c0] * rsqrtf(var0 + BN_EPS);
    float B0 = beta[c0] - mu0 * A0;
    float mu1 = stats[c1] * (1.0f / NN);
    float var1 = stats[DD + c1] * (1.0f / NN) - mu1 * mu1;
    float A1 = gamma[c1] * rsqrtf(var1 + BN_EPS);
    float B1 = beta[c1] - mu1 * A1;

    float ax = 0.f, ay = 0.f;
    int beg = gptr[g], end = gptr[g + 1];
    for (int r = beg + wave; r < end; r += 4) {
        unsigned int u = ((const unsigned int*)(Z + (size_t)r * DD))[lane];
        ax += fmaxf(0.f, fmaf(b2f((unsigned short)(u & 0xffff)), A0, B0));
        ay += fmaxf(0.f, fmaf(b2f((unsigned short)(u >> 16)), A1, B1));
    }
    red[wave][lane] = make_float2(ax, ay);
    __syncthreads();
    if (threadIdx.x < 64) {
        float2 a = red[0][lane], b = red[1][lane], c = red[2][lane], d = red[3][lane];
        ((float2*)pooledDst)[(size_t)g * 64 + lane] =
            make_float2(a.x + b.x + c.x + d.x, a.y + b.y + c.y + d.y);
    }
}

// pooled[g] = sum of raw f32 x rows
__global__ __launch_bounds__(256) void pool_x(const float* __restrict__ src,
                                              const int* __restrict__ gptr,
                                              float* __restrict__ dst) {
    __shared__ float2 red[4][64];
    int g = blockIdx.x;
    int wave = threadIdx.x >> 6, lane = threadIdx.x & 63;
    float ax = 0.f, ay = 0.f;
    int beg = gptr[g], end = gptr[g + 1];
    for (int r = beg + wave; r < end; r += 4) {
        float2 v = ((const float2*)(src + (size_t)r * DD))[lane];
        ax += v.x; ay += v.y;
    }
    red[wave][lane] = make_float2(ax, ay);
    __syncthreads();
    if (threadIdx.x < 64) {
        float2 a = red[0][lane], b = red[1][lane], c = red[2][lane], d = red[3][lane];
        ((float2*)dst)[(size_t)g * 64 + lane] =
            make_float2(a.x + b.x + c.x + d.x, a.y + b.y + c.y + d.y);
    }
}

// ---------------- classifier + log_softmax ----------------

__global__ __launch_bounds__(64) void final_kernel(const float* __restrict__ pooled,
                                                   const float* __restrict__ fcW,
                                                   const float* __restrict__ fcb,
                                                   float* __restrict__ out) {
    int g = blockIdx.x;
    int lane = threadIdx.x;
    float acc[CC];
#pragma unroll
    for (int c = 0; c < CC; ++c) acc[c] = 0.f;
    for (int i = 0; i < LL + 1; ++i) {
        const float* P = pooled + ((size_t)i * GG + g) * DD;
        const float* Wf = fcW + (size_t)i * DD * CC;
        for (int k = lane; k < DD; k += 64) {
            float p = P[k];
            const float* wr = Wf + k * CC;
#pragma unroll
            for (int c = 0; c < CC; ++c) acc[c] = fmaf(p, wr[c], acc[c]);
        }
    }
#pragma unroll
    for (int c = 0; c < CC; ++c)
        for (int off = 32; off > 0; off >>= 1) acc[c] += __shfl_down(acc[c], off);
    if (lane == 0) {
#pragma unroll
        for (int c = 0; c < CC; ++c) {
            float b = 0.f;
            for (int i = 0; i < LL + 1; ++i) b += fcb[i * CC + c];
            acc[c] += b;
        }
        float m = acc[0];
#pragma unroll
        for (int c = 1; c < CC; ++c) m = fmaxf(m, acc[c]);
        float se = 0.f;
#pragma unroll
        for (int c = 0; c < CC; ++c) se += expf(acc[c] - m);
        float lse = m + logf(se);
#pragma unroll
        for (int c = 0; c < CC; ++c) out[(size_t)g * CC + c] = acc[c] - lse;
    }
}

// ---------------- launch ----------------

extern "C" void kernel_launch(void* const* d_in, const int* in_sizes, int n_in,
                              void* d_out, int out_size, void* d_ws, size_t ws_size,
                              hipStream_t stream) {
    const float* x     = (const float*)d_in[0];
    const int*   ei    = (const int*)d_in[1];
    const int*   batch = (const int*)d_in[2];
    const float* Wc1   = (const float*)d_in[3];
    const float* bc1   = (const float*)d_in[4];
    const float* Wc2   = (const float*)d_in[5];
    const float* bc2   = (const float*)d_in[6];
    const float* g_mid = (const float*)d_in[7];
    const float* b_mid = (const float*)d_in[8];
    const float* g_out = (const float*)d_in[9];
    const float* b_out = (const float*)d_in[10];
    const float* fcW   = (const float*)d_in[11];
    const float* fcb   = (const float*)d_in[12];
    float* out = (float*)d_out;

    char* p = (char*)d_ws;
    unsigned short* xb   = (unsigned short*)p; p += (size_t)NN * DD * 2;
    unsigned short* aggb = (unsigned short*)p; p += (size_t)NN * DD * 2;
    unsigned short* z1b  = (unsigned short*)p; p += (size_t)NN * DD * 2;
    unsigned short* z2b  = (unsigned short*)p; p += (size_t)NN * DD * 2;
    unsigned short* WTb  = (unsigned short*)p; p += (size_t)8 * DD * DD * 2;
    float* pooled = (float*)p; p += (size_t)(LL + 1) * GG * DD * 4;
    float* statb  = (float*)p; p += 8 * 256 * 4;
    int* deg    = (int*)p; p += (size_t)NN * 4;   // contiguous with statb for joint memset
    int* rowptr = (int*)p; p += (size_t)(NN + 16) * 4;
    int* cursor = (int*)p; p += (size_t)NN * 4;
    int* csr    = (int*)p; p += (size_t)EE * 4;
    int* gptr   = (int*)p; p += (size_t)(GG + 16) * 4;
    int* bsum1  = (int*)p; p += 64 * 4;

    hipMemsetAsync(statb, 0, (size_t)(8 * 256) * 4 + (size_t)NN * 4, stream);

    const int* src = ei;
    const int* dst = ei + EE;

    cvt_bf16<<<(NN * DD / 2) / 256, 256, 0, stream>>>(x, xb);
    prep_weights<<<(8 * DD * DD) / 256, 256, 0, stream>>>(Wc1, Wc2, WTb);

    hist_kernel<<<(EE + 255) / 256, 256, 0, stream>>>(dst, deg, EE);
    const int nb = (NN + 1023) / 1024;  // 49
    block_sums<<<nb, 256, 0, stream>>>(deg, bsum1, NN);
    scan_bsums<<<1, 256, 0, stream>>>(bsum1, nb);
    scan_final<<<nb, 256, 0, stream>>>(deg, bsum1, rowptr, cursor, NN);
    fill_csr<<<(EE + 255) / 256, 256, 0, stream>>>(src, dst, cursor, csr);
    gptr_search<<<3, 256, 0, stream>>>(batch, gptr);
    pool_x<<<GG, 256, 0, stream>>>(x, gptr, pooled);

    const int gemmGrid = (NN + 127) / 128;  // 391
    const int aggGrid = (NN + 3) / 4;
    for (int l = 0; l < LL; ++l) {
        if (l == 0) {
            aggregate_k<false><<<aggGrid, 256, 0, stream>>>(
                xb, rowptr, csr, nullptr, nullptr, nullptr, aggb);
        } else {
            aggregate_k<true><<<aggGrid, 256, 0, stream>>>(
                z2b, rowptr, csr, statb + (size_t)(2 * (l - 1) + 1) * 256,
                g_out + (size_t)(l - 1) * DD, b_out + (size_t)(l - 1) * DD, aggb);
        }
        gemm_mfma<<<gemmGrid, 256, 0, stream>>>(
            aggb, WTb + (size_t)l * DD * DD, bc1 + (size_t)l * DD,
            nullptr, nullptr, nullptr,
            z1b, statb + (size_t)(2 * l) * 256);
        gemm_mfma<<<gemmGrid, 256, 0, stream>>>(
            z1b, WTb + (size_t)(4 + l) * DD * DD, bc2 + (size_t)l * DD,
            statb + (size_t)(2 * l) * 256, g_mid + (size_t)l * DD, b_mid + (size_t)l * DD,
            z2b, statb + (size_t)(2 * l + 1) * 256);
        bn_pool<<<GG, 256, 0, stream>>>(
            z2b, statb + (size_t)(2 * l + 1) * 256,
            g_out + (size_t)l * DD, b_out + (size_t)l * DD, gptr,
            pooled + (size_t)(l + 1) * GG * DD);
    }
    final_kernel<<<GG, 64, 0, stream>>>(pooled, fcW, fcb, out);
}

// Round 4
// 418.912 us; speedup vs baseline: 3.4652x; 1.0272x over previous
//
#include <hip/hip_runtime.h>
#include <hip/hip_bf16.h>

#define NN 50000
#define EE 600000
#define DD 128
#define LL 4
#define CC 10
#define GG 512
#define BN_EPS 1e-5f

typedef __attribute__((ext_vector_type(8))) short short8;
typedef __attribute__((ext_vector_type(4))) float f32x4;

__device__ __forceinline__ unsigned short f2b(float f) {
    union { float f; unsigned int u; } v; v.f = f;
    unsigned int u = v.u;
    unsigned int r = (u + 0x7fffu + ((u >> 16) & 1u)) >> 16;
    return (unsigned short)r;
}
__device__ __forceinline__ float b2f(unsigned short h) {
    union { unsigned int u; float f; } v; v.u = ((unsigned int)h) << 16;
    return v.f;
}

// ---------------- weights: WTb[mat][n][k] = W[mat][k][n], bf16 ----------------

__global__ __launch_bounds__(256) void prep_weights(const float* __restrict__ Wc1,
                                                    const float* __restrict__ Wc2,
                                                    unsigned short* __restrict__ WTb) {
    int idx = blockIdx.x * 256 + threadIdx.x;    // 131072 total
    int mat = idx >> 14;
    int n = (idx >> 7) & 127;
    int k = idx & 127;
    const float* srcp = (mat < 4) ? (Wc1 + (size_t)mat * DD * DD)
                                  : (Wc2 + (size_t)(mat - 4) * DD * DD);
    WTb[idx] = f2b(srcp[k * DD + n]);
}

// ---------------- CSR build ----------------

__global__ void hist_kernel(const int* __restrict__ idx, int* __restrict__ cnt, int n) {
    int i = blockIdx.x * blockDim.x + threadIdx.x;
    if (i < n) atomicAdd(&cnt[idx[i]], 1);
}

__global__ __launch_bounds__(256) void block_sums(const int* __restrict__ in,
                                                  int* __restrict__ bsums, int n) {
    __shared__ int red[256];
    int b = blockIdx.x, t = threadIdx.x;
    int base = b * 1024 + t * 4;
    int s = 0;
    if (base + 3 < n) {
        int4 v = *(const int4*)(in + base);
        s = v.x + v.y + v.z + v.w;
    } else {
        for (int i = 0; i < 4; ++i) if (base + i < n) s += in[base + i];
    }
    red[t] = s;
    __syncthreads();
    for (int off = 128; off > 0; off >>= 1) {
        if (t < off) red[t] += red[t + off];
        __syncthreads();
    }
    if (t == 0) bsums[b] = red[0];
}

__global__ __launch_bounds__(256) void scan_bsums(int* __restrict__ bsums, int nb) {
    __shared__ int red[256];
    int t = threadIdx.x;
    int v = (t < nb) ? bsums[t] : 0;
    red[t] = v;
    __syncthreads();
    for (int off = 1; off < 256; off <<= 1) {
        int u = (t >= off) ? red[t - off] : 0;
        __syncthreads();
        red[t] += u;
        __syncthreads();
    }
    if (t < nb) bsums[t] = red[t] - v;
    if (t == 0) bsums[nb] = red[255];
}

__global__ __launch_bounds__(256) void scan_final(const int* __restrict__ in,
                                                  const int* __restrict__ bsums,
                                                  int* __restrict__ out,
                                                  int* __restrict__ out2, int n) {
    __shared__ int red[256];
    int b = blockIdx.x, t = threadIdx.x;
    int base = b * 1024 + t * 4;
    int v[4];
    int s = 0;
#pragma unroll
    for (int i = 0; i < 4; ++i) {
        v[i] = (base + i < n) ? in[base + i] : 0;
        s += v[i];
    }
    red[t] = s;
    __syncthreads();
    for (int off = 1; off < 256; off <<= 1) {
        int u = (t >= off) ? red[t - off] : 0;
        __syncthreads();
        red[t] += u;
        __syncthreads();
    }
    int run = bsums[b] + red[t] - s;
#pragma unroll
    for (int i = 0; i < 4; ++i) {
        if (base + i < n) {
            out[base + i] = run;
            if (out2) out2[base + i] = run;
            run += v[i];
        }
    }
    if (b == (int)gridDim.x - 1 && t == 255) out[n] = run;
}

__global__ void fill_csr(const int* __restrict__ src, const int* __restrict__ dst,
                         int* __restrict__ cursor, int* __restrict__ csr) {
    int e = blockIdx.x * blockDim.x + threadIdx.x;
    if (e < EE) {
        int d = dst[e];
        int pos = atomicAdd(&cursor[d], 1);
        csr[pos] = src[e];
    }
}

__global__ void gptr_search(const int* __restrict__ batch, int* __restrict__ gptr) {
    int g = blockIdx.x * blockDim.x + threadIdx.x;
    if (g > GG) return;
    int lo = 0, hi = NN;
    while (lo < hi) {
        int mid = (lo + hi) >> 1;
        if (batch[mid] < g) lo = mid + 1; else hi = mid;
    }
    gptr[g] = lo;
}

// ---------------- aggregation, 16-lane x 4-edge dwordx4 gathers ----------------
// out[n] = t(h[n]) + sum_{src} t(h[src]),  t = BN-affine+ReLU if BN else identity.
// Wave layout: slot = lane>>4 (edge slot), seg = lane&15 (16B column segment).

template <bool BN>
__global__ __launch_bounds__(256) void aggregate_k(const unsigned short* __restrict__ hb,
                                                   const int* __restrict__ rowptr,
                                                   const int* __restrict__ csr,
                                                   const float* __restrict__ stats,
                                                   const float* __restrict__ gamma,
                                                   const float* __restrict__ beta,
                                                   unsigned short* __restrict__ outb) {
    int node = blockIdx.x * 4 + (threadIdx.x >> 6);
    if (node >= NN) return;
    const int lane = threadIdx.x & 63;
    const int seg = lane & 15;
    const int slot = lane >> 4;

    float A[8], B[8];
    if (BN) {
#pragma unroll
        for (int j = 0; j < 8; ++j) {
            int c = seg * 8 + j;
            float mu = stats[c] * (1.0f / NN);
            float var = stats[DD + c] * (1.0f / NN) - mu * mu;
            A[j] = gamma[c] * rsqrtf(var + BN_EPS);
            B[j] = beta[c] - mu * A[j];
        }
    }

    const uint4* hb4 = (const uint4*)hb;            // row stride = 16 uint4
    uint4 self = hb4[(size_t)node * 16 + seg];      // preload to hide latency

    float acc[8];
#pragma unroll
    for (int j = 0; j < 8; ++j) acc[j] = 0.f;

    const int beg = rowptr[node], end = rowptr[node + 1];
    for (int e = beg; e < end; e += 16) {
        int idx[4];
        bool val[4];
#pragma unroll
        for (int i = 0; i < 4; ++i) {
            int t = e + i * 4 + slot;
            val[i] = (t < end);
            idx[i] = csr[val[i] ? t : beg];
        }
        uint4 v[4];
#pragma unroll
        for (int i = 0; i < 4; ++i) v[i] = hb4[(size_t)idx[i] * 16 + seg];
#pragma unroll
        for (int i = 0; i < 4; ++i) {
            if (val[i]) {
#pragma unroll
                for (int j = 0; j < 4; ++j) {
                    unsigned int u = ((unsigned int*)&v[i])[j];
                    float x = b2f((unsigned short)(u & 0xffff));
                    float y = b2f((unsigned short)(u >> 16));
                    if (BN) {
                        x = fmaxf(0.f, fmaf(x, A[2 * j], B[2 * j]));
                        y = fmaxf(0.f, fmaf(y, A[2 * j + 1], B[2 * j + 1]));
                    }
                    acc[2 * j] += x;
                    acc[2 * j + 1] += y;
                }
            }
        }
    }

    // reduce the 4 edge slots -> full neighbor sum on every lane
#pragma unroll
    for (int j = 0; j < 8; ++j) {
        acc[j] += __shfl_xor(acc[j], 16);
        acc[j] += __shfl_xor(acc[j], 32);
    }

    if (slot == 0) {
        uint4 o;
#pragma unroll
        for (int j = 0; j < 4; ++j) {
            unsigned int u = ((unsigned int*)&self)[j];
            float x = b2f((unsigned short)(u & 0xffff));
            float y = b2f((unsigned short)(u >> 16));
            if (BN) {
                x = fmaxf(0.f, fmaf(x, A[2 * j], B[2 * j]));
                y = fmaxf(0.f, fmaf(y, A[2 * j + 1], B[2 * j + 1]));
            }
            ((unsigned int*)&o)[j] =
                (unsigned int)f2b(acc[2 * j] + x) | ((unsigned int)f2b(acc[2 * j + 1] + y) << 16);
        }
        ((uint4*)outb)[(size_t)node * 16 + seg] = o;
    }
}

// ---------------- MFMA GEMM: Out = (bn?)(Z) @ W + bias, + column stats ----------------

__global__ __launch_bounds__(256) void gemm_mfma(
    const unsigned short* __restrict__ Ab,
    const unsigned short* __restrict__ WTb,
    const float* __restrict__ bias,
    const float* __restrict__ bnStatsIn,
    const float* __restrict__ gamma, const float* __restrict__ beta,
    unsigned short* __restrict__ Outb,
    float* __restrict__ statsOut)
{
    __shared__ unsigned short As[128 * 128];
    __shared__ unsigned short Bs[128 * 128];
    __shared__ float AbnS[DD], BbnS[DD];
    __shared__ float colred[2][DD];

    const int tid = threadIdx.x;
    const int row0 = blockIdx.x * 128;
    const bool doBn = (bnStatsIn != nullptr);

    if (tid < DD) {
        colred[0][tid] = 0.f;
        colred[1][tid] = 0.f;
        if (doBn) {
            float mu = bnStatsIn[tid] * (1.0f / NN);
            float var = bnStatsIn[DD + tid] * (1.0f / NN) - mu * mu;
            float A = gamma[tid] * rsqrtf(var + BN_EPS);
            AbnS[tid] = A;
            BbnS[tid] = beta[tid] - mu * A;
        }
    }
    __syncthreads();

    const uint4* Bg = (const uint4*)WTb;
#pragma unroll
    for (int i = 0; i < 8; ++i) {
        int c = tid + i * 256;
        int row = c >> 4, seg = c & 15;
        uint4 v = Bg[c];
        int byte = (row * 256 + seg * 16) ^ ((row & 7) << 4);
        *(uint4*)((char*)Bs + byte) = v;
    }
#pragma unroll
    for (int i = 0; i < 8; ++i) {
        int c = tid + i * 256;
        int row = c >> 4, seg = c & 15;
        int gr = row0 + row;
        uint4 v = make_uint4(0u, 0u, 0u, 0u);
        if (gr < NN) v = ((const uint4*)(Ab + (size_t)gr * DD))[seg];
        if (doBn) {
            int k0 = seg * 8;
#pragma unroll
            for (int e = 0; e < 4; ++e) {
                unsigned int u = ((unsigned int*)&v)[e];
                int cidx = k0 + 2 * e;
                float lo = fmaxf(0.f, fmaf(b2f((unsigned short)(u & 0xffff)), AbnS[cidx], BbnS[cidx]));
                float hi = fmaxf(0.f, fmaf(b2f((unsigned short)(u >> 16)), AbnS[cidx + 1], BbnS[cidx + 1]));
                ((unsigned int*)&v)[e] = (unsigned int)f2b(lo) | ((unsigned int)f2b(hi) << 16);
            }
        }
        int byte = (row * 256 + seg * 16) ^ ((row & 7) << 4);
        *(uint4*)((char*)As + byte) = v;
    }
    __syncthreads();

    const int wave = tid >> 6, lane = tid & 63;
    const int fr = lane & 15, fq = lane >> 4;
    const int wr0 = wave * 32;

    f32x4 acc[2][8];
#pragma unroll
    for (int m = 0; m < 2; ++m)
#pragma unroll
        for (int n = 0; n < 8; ++n) acc[m][n] = (f32x4)0.f;

#pragma unroll
    for (int kk = 0; kk < 4; ++kk) {
        int kbyte = kk * 64 + fq * 16;
        short8 a[2], b[8];
#pragma unroll
        for (int m = 0; m < 2; ++m) {
            int row = wr0 + m * 16 + fr;
            a[m] = *(const short8*)((const char*)As + ((row * 256 + kbyte) ^ ((row & 7) << 4)));
        }
#pragma unroll
        for (int n = 0; n < 8; ++n) {
            int row = n * 16 + fr;
            b[n] = *(const short8*)((const char*)Bs + ((row * 256 + kbyte) ^ ((row & 7) << 4)));
        }
#pragma unroll
        for (int m = 0; m < 2; ++m)
#pragma unroll
            for (int n = 0; n < 8; ++n)
                acc[m][n] = __builtin_amdgcn_mfma_f32_16x16x32_bf16(a[m], b[n], acc[m][n], 0, 0, 0);
    }

    float bias_n[8], s[8], q[8];
#pragma unroll
    for (int n = 0; n < 8; ++n) {
        bias_n[n] = bias[n * 16 + fr];
        s[n] = 0.f;
        q[n] = 0.f;
    }
#pragma unroll
    for (int m = 0; m < 2; ++m) {
        int rbase = row0 + wr0 + m * 16 + fq * 4;
#pragma unroll
        for (int j = 0; j < 4; ++j) {
            int gr = rbase + j;
            if (gr < NN) {
#pragma unroll
                for (int n = 0; n < 8; ++n) {
                    float o = acc[m][n][j] + bias_n[n];
                    Outb[(size_t)gr * DD + n * 16 + fr] = f2b(o);
                    s[n] += o;
                    q[n] += o * o;
                }
            }
        }
    }
    if (statsOut) {
#pragma unroll
        for (int n = 0; n < 8; ++n) {
            s[n] += __shfl_xor(s[n], 16);
            s[n] += __shfl_xor(s[n], 32);
            q[n] += __shfl_xor(q[n], 16);
            q[n] += __shfl_xor(q[n], 32);
        }
        if (fq == 0) {
#pragma unroll
            for (int n = 0; n < 8; ++n) {
                atomicAdd(&colred[0][n * 16 + fr], s[n]);
                atomicAdd(&colred[1][n * 16 + fr], q[n]);
            }
        }
        __syncthreads();
        if (tid < DD) {
            atomicAdd(&statsOut[tid], colred[0][tid]);
            atomicAdd(&statsOut[DD + tid], colred[1][tid]);
        }
    }
}

// ---------------- pooled[g] = sum_{rows of g} relu(bn(Z[r])) ----------------

__global__ __launch_bounds__(256) void bn_pool(const unsigned short* __restrict__ Z,
                                               const float* __restrict__ stats,
                                               const float* __restrict__ gamma,
                                               const float* __restrict__ beta,
                                               const int* __restrict__ gptr,
                                               float* __restrict__ pooledDst) {
    __shared__ float2 red[4][64];
    int g = blockIdx.x;
    int wave = threadIdx.x >> 6, lane = threadIdx.x & 63;
    int c0 = lane * 2, c1 = c0 + 1;
    float mu0 = stats[c0] * (1.0f / NN);
    float var0 = stats[DD + c0] * (1.0f / NN) - mu0 * mu0;
    float A0 = gamma[c0] * rsqrtf(var0 + BN_EPS);
    float B0 = beta[c0] - mu0 * A0;
    float mu1 = stats[c1] * (1.0f / NN);
    float var1 = stats[DD + c1] * (1.0f / NN) - mu1 * mu1;
    float A1 = gamma[c1] * rsqrtf(var1 + BN_EPS);
    float B1 = beta[c1] - mu1 * A1;

    float ax = 0.f, ay = 0.f;
    int beg = gptr[g], end = gptr[g + 1];
    for (int r = beg + wave; r < end; r += 4) {
        unsigned int u = ((const unsigned int*)(Z + (size_t)r * DD))[lane];
        ax += fmaxf(0.f, fmaf(b2f((unsigned short)(u & 0xffff)), A0, B0));
        ay += fmaxf(0.f, fmaf(b2f((unsigned short)(u >> 16)), A1, B1));
    }
    red[wave][lane] = make_float2(ax, ay);
    __syncthreads();
    if (threadIdx.x < 64) {
        float2 a = red[0][lane], b = red[1][lane], c = red[2][lane], d = red[3][lane];
        ((float2*)pooledDst)[(size_t)g * 64 + lane] =
            make_float2(a.x + b.x + c.x + d.x, a.y + b.y + c.y + d.y);
    }
}

// ---------------- fused: xb = bf16(x), pooled[g] = sum rows of g ----------------

__global__ __launch_bounds__(256) void cvt_pool_x(const float* __restrict__ x,
                                                  const int* __restrict__ gptr,
                                                  unsigned short* __restrict__ xb,
                                                  float* __restrict__ dst) {
    __shared__ float2 red[4][64];
    int g = blockIdx.x;
    int wave = threadIdx.x >> 6, lane = threadIdx.x & 63;
    float ax = 0.f, ay = 0.f;
    int beg = gptr[g], end = gptr[g + 1];
    for (int r = beg + wave; r < end; r += 4) {
        float2 v = ((const float2*)(x + (size_t)r * DD))[lane];
        ax += v.x; ay += v.y;
        ((unsigned int*)(xb + (size_t)r * DD))[lane] =
            (unsigned int)f2b(v.x) | ((unsigned int)f2b(v.y) << 16);
    }
    red[wave][lane] = make_float2(ax, ay);
    __syncthreads();
    if (threadIdx.x < 64) {
        float2 a = red[0][lane], b = red[1][lane], c = red[2][lane], d = red[3][lane];
        ((float2*)dst)[(size_t)g * 64 + lane] =
            make_float2(a.x + b.x + c.x + d.x, a.y + b.y + c.y + d.y);
    }
}

// ---------------- classifier + log_softmax ----------------

__global__ __launch_bounds__(64) void final_kernel(const float* __restrict__ pooled,
                                                   const float* __restrict__ fcW,
                                                   const float* __restrict__ fcb,
                                                   float* __restrict__ out) {
    int g = blockIdx.x;
    int lane = threadIdx.x;
    float acc[CC];
#pragma unroll
    for (int c = 0; c < CC; ++c) acc[c] = 0.f;
    for (int i = 0; i < LL + 1; ++i) {
        const float* P = pooled + ((size_t)i * GG + g) * DD;
        const float* Wf = fcW + (size_t)i * DD * CC;
        for (int k = lane; k < DD; k += 64) {
            float p = P[k];
            const float* wr = Wf + k * CC;
#pragma unroll
            for (int c = 0; c < CC; ++c) acc[c] = fmaf(p, wr[c], acc[c]);
        }
    }
#pragma unroll
    for (int c = 0; c < CC; ++c)
        for (int off = 32; off > 0; off >>= 1) acc[c] += __shfl_down(acc[c], off);
    if (lane == 0) {
#pragma unroll
        for (int c = 0; c < CC; ++c) {
            float b = 0.f;
            for (int i = 0; i < LL + 1; ++i) b += fcb[i * CC + c];
            acc[c] += b;
        }
        float m = acc[0];
#pragma unroll
        for (int c = 1; c < CC; ++c) m = fmaxf(m, acc[c]);
        float se = 0.f;
#pragma unroll
        for (int c = 0; c < CC; ++c) se += expf(acc[c] - m);
        float lse = m + logf(se);
#pragma unroll
        for (int c = 0; c < CC; ++c) out[(size_t)g * CC + c] = acc[c] - lse;
    }
}

// ---------------- launch ----------------

extern "C" void kernel_launch(void* const* d_in, const int* in_sizes, int n_in,
                              void* d_out, int out_size, void* d_ws, size_t ws_size,
                              hipStream_t stream) {
    const float* x     = (const float*)d_in[0];
    const int*   ei    = (const int*)d_in[1];
    const int*   batch = (const int*)d_in[2];
    const float* Wc1   = (const float*)d_in[3];
    const float* bc1   = (const float*)d_in[4];
    const float* Wc2   = (const float*)d_in[5];
    const float* bc2   = (const float*)d_in[6];
    const float* g_mid = (const float*)d_in[7];
    const float* b_mid = (const float*)d_in[8];
    const float* g_out = (const float*)d_in[9];
    const float* b_out = (const float*)d_in[10];
    const float* fcW   = (const float*)d_in[11];
    const float* fcb   = (const float*)d_in[12];
    float* out = (float*)d_out;

    char* p = (char*)d_ws;
    unsigned short* xb   = (unsigned short*)p; p += (size_t)NN * DD * 2;
    unsigned short* aggb = (unsigned short*)p; p += (size_t)NN * DD * 2;
    unsigned short* z1b  = (unsigned short*)p; p += (size_t)NN * DD * 2;
    unsigned short* z2b  = (unsigned short*)p; p += (size_t)NN * DD * 2;
    unsigned short* WTb  = (unsigned short*)p; p += (size_t)8 * DD * DD * 2;
    float* pooled = (float*)p; p += (size_t)(LL + 1) * GG * DD * 4;
    float* statb  = (float*)p; p += 8 * 256 * 4;
    int* deg    = (int*)p; p += (size_t)NN * 4;   // contiguous with statb for joint memset
    int* rowptr = (int*)p; p += (size_t)(NN + 16) * 4;
    int* cursor = (int*)p; p += (size_t)NN * 4;
    int* csr    = (int*)p; p += (size_t)EE * 4;
    int* gptr   = (int*)p; p += (size_t)(GG + 16) * 4;
    int* bsum1  = (int*)p; p += 64 * 4;

    hipMemsetAsync(statb, 0, (size_t)(8 * 256) * 4 + (size_t)NN * 4, stream);

    const int* src = ei;
    const int* dst = ei + EE;

    prep_weights<<<(8 * DD * DD) / 256, 256, 0, stream>>>(Wc1, Wc2, WTb);

    hist_kernel<<<(EE + 255) / 256, 256, 0, stream>>>(dst, deg, EE);
    const int nb = (NN + 1023) / 1024;  // 49
    block_sums<<<nb, 256, 0, stream>>>(deg, bsum1, NN);
    scan_bsums<<<1, 256, 0, stream>>>(bsum1, nb);
    scan_final<<<nb, 256, 0, stream>>>(deg, bsum1, rowptr, cursor, NN);
    fill_csr<<<(EE + 255) / 256, 256, 0, stream>>>(src, dst, cursor, csr);
    gptr_search<<<3, 256, 0, stream>>>(batch, gptr);
    cvt_pool_x<<<GG, 256, 0, stream>>>(x, gptr, xb, pooled);

    const int gemmGrid = (NN + 127) / 128;  // 391
    const int aggGrid = (NN + 3) / 4;
    for (int l = 0; l < LL; ++l) {
        if (l == 0) {
            aggregate_k<false><<<aggGrid, 256, 0, stream>>>(
                xb, rowptr, csr, nullptr, nullptr, nullptr, aggb);
        } else {
            aggregate_k<true><<<aggGrid, 256, 0, stream>>>(
                z2b, rowptr, csr, statb + (size_t)(2 * (l - 1) + 1) * 256,
                g_out + (size_t)(l - 1) * DD, b_out + (size_t)(l - 1) * DD, aggb);
        }
        gemm_mfma<<<gemmGrid, 256, 0, stream>>>(
            aggb, WTb + (size_t)l * DD * DD, bc1 + (size_t)l * DD,
            nullptr, nullptr, nullptr,
            z1b, statb + (size_t)(2 * l) * 256);
        gemm_mfma<<<gemmGrid, 256, 0, stream>>>(
            z1b, WTb + (size_t)(4 + l) * DD * DD, bc2 + (size_t)l * DD,
            statb + (size_t)(2 * l) * 256, g_mid + (size_t)l * DD, b_mid + (size_t)l * DD,
            z2b, statb + (size_t)(2 * l + 1) * 256);
        bn_pool<<<GG, 256, 0, stream>>>(
            z2b, statb + (size_t)(2 * l + 1) * 256,
            g_out + (size_t)l * DD, b_out + (size_t)l * DD, gptr,
            pooled + (size_t)(l + 1) * GG * DD);
    }
    final_kernel<<<GG, 64, 0, stream>>>(pooled, fcW, fcb, out);
}

// Round 5
// 406.212 us; speedup vs baseline: 3.5736x; 1.0313x over previous
//
#include <hip/hip_runtime.h>
#include <hip/hip_bf16.h>

#define NN 50000
#define EE 600000
#define DD 128
#define LL 4
#define CC 10
#define GG 512
#define BN_EPS 1e-5f

#define HB_BLOCKS ((EE + 255) / 256)          // 2344
#define PW_BLOCKS ((8 * DD * DD) / 256)       // 512
#define AGG_BLOCKS ((NN + 3) / 4)             // 12500

typedef __attribute__((ext_vector_type(8))) short short8;
typedef __attribute__((ext_vector_type(4))) float f32x4;

__device__ __forceinline__ unsigned short f2b(float f) {
    union { float f; unsigned int u; } v; v.f = f;
    unsigned int u = v.u;
    unsigned int r = (u + 0x7fffu + ((u >> 16) & 1u)) >> 16;
    return (unsigned short)r;
}
__device__ __forceinline__ float b2f(unsigned short h) {
    union { unsigned int u; float f; } v; v.u = ((unsigned int)h) << 16;
    return v.f;
}

// ---------------- setup: hist(deg) + prep_weights + gptr_search in one dispatch ----------------

__global__ __launch_bounds__(256) void setup_kernel(const int* __restrict__ dst,
                                                    int* __restrict__ deg,
                                                    const float* __restrict__ Wc1,
                                                    const float* __restrict__ Wc2,
                                                    unsigned short* __restrict__ WTb,
                                                    const int* __restrict__ batch,
                                                    int* __restrict__ gptr) {
    int b = blockIdx.x;
    if (b < HB_BLOCKS) {
        int i = b * 256 + threadIdx.x;
        if (i < EE) atomicAdd(&deg[dst[i]], 1);
    } else if (b < HB_BLOCKS + PW_BLOCKS) {
        int idx = (b - HB_BLOCKS) * 256 + threadIdx.x;   // 131072 total
        int mat = idx >> 14;
        int n = (idx >> 7) & 127;
        int k = idx & 127;
        const float* srcp = (mat < 4) ? (Wc1 + (size_t)mat * DD * DD)
                                      : (Wc2 + (size_t)(mat - 4) * DD * DD);
        WTb[idx] = f2b(srcp[k * DD + n]);
    } else {
        int g = (b - HB_BLOCKS - PW_BLOCKS) * 256 + threadIdx.x;
        if (g > GG) return;
        int lo = 0, hi = NN;
        while (lo < hi) {
            int mid = (lo + hi) >> 1;
            if (batch[mid] < g) lo = mid + 1; else hi = mid;
        }
        gptr[g] = lo;
    }
}

// ---------------- CSR scan chain ----------------

__global__ __launch_bounds__(256) void block_sums(const int* __restrict__ in,
                                                  int* __restrict__ bsums, int n) {
    __shared__ int red[256];
    int b = blockIdx.x, t = threadIdx.x;
    int base = b * 1024 + t * 4;
    int s = 0;
    if (base + 3 < n) {
        int4 v = *(const int4*)(in + base);
        s = v.x + v.y + v.z + v.w;
    } else {
        for (int i = 0; i < 4; ++i) if (base + i < n) s += in[base + i];
    }
    red[t] = s;
    __syncthreads();
    for (int off = 128; off > 0; off >>= 1) {
        if (t < off) red[t] += red[t + off];
        __syncthreads();
    }
    if (t == 0) bsums[b] = red[0];
}

__global__ __launch_bounds__(256) void scan_bsums(int* __restrict__ bsums, int nb) {
    __shared__ int red[256];
    int t = threadIdx.x;
    int v = (t < nb) ? bsums[t] : 0;
    red[t] = v;
    __syncthreads();
    for (int off = 1; off < 256; off <<= 1) {
        int u = (t >= off) ? red[t - off] : 0;
        __syncthreads();
        red[t] += u;
        __syncthreads();
    }
    if (t < nb) bsums[t] = red[t] - v;
    if (t == 0) bsums[nb] = red[255];
}

__global__ __launch_bounds__(256) void scan_final(const int* __restrict__ in,
                                                  const int* __restrict__ bsums,
                                                  int* __restrict__ out,
                                                  int* __restrict__ out2, int n) {
    __shared__ int red[256];
    int b = blockIdx.x, t = threadIdx.x;
    int base = b * 1024 + t * 4;
    int v[4];
    int s = 0;
#pragma unroll
    for (int i = 0; i < 4; ++i) {
        v[i] = (base + i < n) ? in[base + i] : 0;
        s += v[i];
    }
    red[t] = s;
    __syncthreads();
    for (int off = 1; off < 256; off <<= 1) {
        int u = (t >= off) ? red[t - off] : 0;
        __syncthreads();
        red[t] += u;
        __syncthreads();
    }
    int run = bsums[b] + red[t] - s;
#pragma unroll
    for (int i = 0; i < 4; ++i) {
        if (base + i < n) {
            out[base + i] = run;
            if (out2) out2[base + i] = run;
            run += v[i];
        }
    }
    if (b == (int)gridDim.x - 1 && t == 255) out[n] = run;
}

__global__ void fill_csr(const int* __restrict__ src, const int* __restrict__ dst,
                         int* __restrict__ cursor, int* __restrict__ csr) {
    int e = blockIdx.x * blockDim.x + threadIdx.x;
    if (e < EE) {
        int d = dst[e];
        int pos = atomicAdd(&cursor[d], 1);
        csr[pos] = src[e];
    }
}

// ---------------- aggregation body (shared by standalone + fused kernels) ----------------
// out[n] = t(h[n]) + sum_{src} t(h[src]),  t = BN-affine+ReLU if BN else identity.
// One wave per node: slot = lane>>4 (edge slot), seg = lane&15 (16B column segment).

template <bool BN>
__device__ __forceinline__ void agg_node(int node, const unsigned short* __restrict__ hb,
                                         const int* __restrict__ rowptr,
                                         const int* __restrict__ csr,
                                         const float* __restrict__ stats,
                                         const float* __restrict__ gamma,
                                         const float* __restrict__ beta,
                                         unsigned short* __restrict__ outb) {
    const int lane = threadIdx.x & 63;
    const int seg = lane & 15;
    const int slot = lane >> 4;

    float A[8], B[8];
    if (BN) {
#pragma unroll
        for (int j = 0; j < 8; ++j) {
            int c = seg * 8 + j;
            float mu = stats[c] * (1.0f / NN);
            float var = stats[DD + c] * (1.0f / NN) - mu * mu;
            A[j] = gamma[c] * rsqrtf(var + BN_EPS);
            B[j] = beta[c] - mu * A[j];
        }
    }

    const uint4* hb4 = (const uint4*)hb;            // row stride = 16 uint4
    uint4 self = hb4[(size_t)node * 16 + seg];

    float acc[8];
#pragma unroll
    for (int j = 0; j < 8; ++j) acc[j] = 0.f;

    const int beg = rowptr[node], end = rowptr[node + 1];
    for (int e = beg; e < end; e += 16) {
        int idx[4];
        bool val[4];
#pragma unroll
        for (int i = 0; i < 4; ++i) {
            int t = e + i * 4 + slot;
            val[i] = (t < end);
            idx[i] = csr[val[i] ? t : beg];
        }
        uint4 v[4];
#pragma unroll
        for (int i = 0; i < 4; ++i) v[i] = hb4[(size_t)idx[i] * 16 + seg];
#pragma unroll
        for (int i = 0; i < 4; ++i) {
            if (val[i]) {
#pragma unroll
                for (int j = 0; j < 4; ++j) {
                    unsigned int u = ((unsigned int*)&v[i])[j];
                    float x = b2f((unsigned short)(u & 0xffff));
                    float y = b2f((unsigned short)(u >> 16));
                    if (BN) {
                        x = fmaxf(0.f, fmaf(x, A[2 * j], B[2 * j]));
                        y = fmaxf(0.f, fmaf(y, A[2 * j + 1], B[2 * j + 1]));
                    }
                    acc[2 * j] += x;
                    acc[2 * j + 1] += y;
                }
            }
        }
    }

#pragma unroll
    for (int j = 0; j < 8; ++j) {
        acc[j] += __shfl_xor(acc[j], 16);
        acc[j] += __shfl_xor(acc[j], 32);
    }

    if (slot == 0) {
        uint4 o;
#pragma unroll
        for (int j = 0; j < 4; ++j) {
            unsigned int u = ((unsigned int*)&self)[j];
            float x = b2f((unsigned short)(u & 0xffff));
            float y = b2f((unsigned short)(u >> 16));
            if (BN) {
                x = fmaxf(0.f, fmaf(x, A[2 * j], B[2 * j]));
                y = fmaxf(0.f, fmaf(y, A[2 * j + 1], B[2 * j + 1]));
            }
            ((unsigned int*)&o)[j] =
                (unsigned int)f2b(acc[2 * j] + x) | ((unsigned int)f2b(acc[2 * j + 1] + y) << 16);
        }
        ((uint4*)outb)[(size_t)node * 16 + seg] = o;
    }
}

__global__ __launch_bounds__(256) void aggregate_x(const unsigned short* __restrict__ hb,
                                                   const int* __restrict__ rowptr,
                                                   const int* __restrict__ csr,
                                                   unsigned short* __restrict__ outb) {
    int node = blockIdx.x * 4 + (threadIdx.x >> 6);
    if (node >= NN) return;
    agg_node<false>(node, hb, rowptr, csr, nullptr, nullptr, nullptr, outb);
}

// ---------------- MFMA GEMM, W in registers: Out = (bn?)(Z) @ W + bias, + stats ----------------

__global__ __launch_bounds__(256, 2) void gemm_mfma(
    const unsigned short* __restrict__ Ab,   // [NN][128] bf16
    const unsigned short* __restrict__ WTb,  // [128][128] bf16 (WT[n][k])
    const float* __restrict__ bias,
    const float* __restrict__ bnStatsIn,     // null => raw input
    const float* __restrict__ gamma, const float* __restrict__ beta,
    unsigned short* __restrict__ Outb,       // [NN][128] bf16
    float* __restrict__ statsOut)            // [0..127]=colsum, [128..255]=colsumsq
{
    __shared__ unsigned short As[128 * 128];  // 32 KB, XOR-swizzled rows
    __shared__ float AbnS[DD], BbnS[DD];
    __shared__ float colred[2][DD];

    const int tid = threadIdx.x;
    const int row0 = blockIdx.x * 128;
    const bool doBn = (bnStatsIn != nullptr);
    const int lane = tid & 63;
    const int fr = lane & 15, fq = lane >> 4;

    // B fragments: all of W in registers (32 KB total, L2-hot). 8n x 4kk x 16B/lane.
    short8 bfrag[8][4];
#pragma unroll
    for (int n = 0; n < 8; ++n)
#pragma unroll
        for (int kk = 0; kk < 4; ++kk)
            bfrag[n][kk] = *(const short8*)((const char*)WTb + (n * 16 + fr) * 256 + kk * 64 + fq * 16);

    if (tid < DD) {
        colred[0][tid] = 0.f;
        colred[1][tid] = 0.f;
        if (doBn) {
            float mu = bnStatsIn[tid] * (1.0f / NN);
            float var = bnStatsIn[DD + tid] * (1.0f / NN) - mu * mu;
            float A = gamma[tid] * rsqrtf(var + BN_EPS);
            AbnS[tid] = A;
            BbnS[tid] = beta[tid] - mu * A;
        }
    }
    if (doBn) __syncthreads();

    // stage A tile (optional BN+ReLU on load)
#pragma unroll
    for (int i = 0; i < 8; ++i) {
        int c = tid + i * 256;
        int row = c >> 4, seg = c & 15;
        int gr = row0 + row;
        uint4 v = make_uint4(0u, 0u, 0u, 0u);
        if (gr < NN) v = ((const uint4*)(Ab + (size_t)gr * DD))[seg];
        if (doBn) {
            int k0 = seg * 8;
#pragma unroll
            for (int e = 0; e < 4; ++e) {
                unsigned int u = ((unsigned int*)&v)[e];
                int cidx = k0 + 2 * e;
                float lo = fmaxf(0.f, fmaf(b2f((unsigned short)(u & 0xffff)), AbnS[cidx], BbnS[cidx]));
                float hi = fmaxf(0.f, fmaf(b2f((unsigned short)(u >> 16)), AbnS[cidx + 1], BbnS[cidx + 1]));
                ((unsigned int*)&v)[e] = (unsigned int)f2b(lo) | ((unsigned int)f2b(hi) << 16);
            }
        }
        int byte = (row * 256 + seg * 16) ^ ((row & 7) << 4);
        *(uint4*)((char*)As + byte) = v;
    }
    __syncthreads();

    const int wave = tid >> 6;
    const int wr0 = wave * 32;

    f32x4 acc[2][8];
#pragma unroll
    for (int m = 0; m < 2; ++m)
#pragma unroll
        for (int n = 0; n < 8; ++n) acc[m][n] = (f32x4)0.f;

#pragma unroll
    for (int kk = 0; kk < 4; ++kk) {
        int kbyte = kk * 64 + fq * 16;
        short8 a[2];
#pragma unroll
        for (int m = 0; m < 2; ++m) {
            int row = wr0 + m * 16 + fr;
            a[m] = *(const short8*)((const char*)As + ((row * 256 + kbyte) ^ ((row & 7) << 4)));
        }
#pragma unroll
        for (int m = 0; m < 2; ++m)
#pragma unroll
            for (int n = 0; n < 8; ++n)
                acc[m][n] = __builtin_amdgcn_mfma_f32_16x16x32_bf16(a[m], bfrag[n][kk], acc[m][n], 0, 0, 0);
    }

    float bias_n[8], s[8], q[8];
#pragma unroll
    for (int n = 0; n < 8; ++n) {
        bias_n[n] = bias[n * 16 + fr];
        s[n] = 0.f;
        q[n] = 0.f;
    }
#pragma unroll
    for (int m = 0; m < 2; ++m) {
        int rbase = row0 + wr0 + m * 16 + fq * 4;
#pragma unroll
        for (int j = 0; j < 4; ++j) {
            int gr = rbase + j;
            if (gr < NN) {
#pragma unroll
                for (int n = 0; n < 8; ++n) {
                    float o = acc[m][n][j] + bias_n[n];
                    Outb[(size_t)gr * DD + n * 16 + fr] = f2b(o);
                    s[n] += o;
                    q[n] += o * o;
                }
            }
        }
    }
#pragma unroll
    for (int n = 0; n < 8; ++n) {
        s[n] += __shfl_xor(s[n], 16);
        s[n] += __shfl_xor(s[n], 32);
        q[n] += __shfl_xor(q[n], 16);
        q[n] += __shfl_xor(q[n], 32);
    }
    if (fq == 0) {
#pragma unroll
        for (int n = 0; n < 8; ++n) {
            atomicAdd(&colred[0][n * 16 + fr], s[n]);
            atomicAdd(&colred[1][n * 16 + fr], q[n]);
        }
    }
    __syncthreads();
    if (tid < DD) {
        atomicAdd(&statsOut[tid], colred[0][tid]);
        atomicAdd(&statsOut[DD + tid], colred[1][tid]);
    }
}

// ---------------- post_layer: bn_pool (blocks < GG) + next-layer aggregate (rest) ----------------
// LAST: pool blocks also compute the classifier + log_softmax for their graph.

template <bool LAST>
__global__ __launch_bounds__(256) void post_layer(
    const unsigned short* __restrict__ Z,      // z2b of this layer
    const float* __restrict__ stats,           // statb (2l+1)
    const float* __restrict__ gamma,           // g_out[l]
    const float* __restrict__ beta,            // b_out[l]
    const int* __restrict__ gptr,
    const int* __restrict__ rowptr,
    const int* __restrict__ csr,
    float* __restrict__ pooledDst,             // pooled + (l+1)*GG*DD
    unsigned short* __restrict__ aggOut,       // aggb for next layer (unused if LAST)
    const float* __restrict__ pooledAll,       // pooled base (LAST only)
    const float* __restrict__ fcW,
    const float* __restrict__ fcb,
    float* __restrict__ out)
{
    const int bid = blockIdx.x;
    if (bid < GG) {
        __shared__ float2 red[4][64];
        __shared__ float p4[DD];
        const int g = bid;
        const int wave = threadIdx.x >> 6, lane = threadIdx.x & 63;
        const int c0 = lane * 2, c1 = c0 + 1;
        float mu0 = stats[c0] * (1.0f / NN);
        float var0 = stats[DD + c0] * (1.0f / NN) - mu0 * mu0;
        float A0 = gamma[c0] * rsqrtf(var0 + BN_EPS);
        float B0 = beta[c0] - mu0 * A0;
        float mu1 = stats[c1] * (1.0f / NN);
        float var1 = stats[DD + c1] * (1.0f / NN) - mu1 * mu1;
        float A1 = gamma[c1] * rsqrtf(var1 + BN_EPS);
        float B1 = beta[c1] - mu1 * A1;

        float ax = 0.f, ay = 0.f;
        int beg = gptr[g], end = gptr[g + 1];
        for (int r = beg + wave; r < end; r += 4) {
            unsigned int u = ((const unsigned int*)(Z + (size_t)r * DD))[lane];
            ax += fmaxf(0.f, fmaf(b2f((unsigned short)(u & 0xffff)), A0, B0));
            ay += fmaxf(0.f, fmaf(b2f((unsigned short)(u >> 16)), A1, B1));
        }
        red[wave][lane] = make_float2(ax, ay);
        __syncthreads();
        if (threadIdx.x < 64) {
            float2 a = red[0][lane], b = red[1][lane], c = red[2][lane], d = red[3][lane];
            float2 r2 = make_float2(a.x + b.x + c.x + d.x, a.y + b.y + c.y + d.y);
            ((float2*)pooledDst)[(size_t)g * 64 + lane] = r2;
            if (LAST) {
                p4[c0] = r2.x;
                p4[c1] = r2.y;
            }
        }
        if (LAST) {
            __syncthreads();
            if (threadIdx.x < 64) {
                float acc[CC];
#pragma unroll
                for (int c = 0; c < CC; ++c) acc[c] = 0.f;
                for (int i = 0; i < LL + 1; ++i) {
                    const float* Wf = fcW + (size_t)i * DD * CC;
                    for (int k = lane; k < DD; k += 64) {
                        float pv = (i == LL) ? p4[k] : pooledAll[((size_t)i * GG + g) * DD + k];
                        const float* wr = Wf + k * CC;
#pragma unroll
                        for (int c = 0; c < CC; ++c) acc[c] = fmaf(pv, wr[c], acc[c]);
                    }
                }
#pragma unroll
                for (int c = 0; c < CC; ++c)
                    for (int off = 32; off > 0; off >>= 1) acc[c] += __shfl_down(acc[c], off);
                if (lane == 0) {
#pragma unroll
                    for (int c = 0; c < CC; ++c) {
                        float b = 0.f;
                        for (int i = 0; i < LL + 1; ++i) b += fcb[i * CC + c];
                        acc[c] += b;
                    }
                    float m = acc[0];
#pragma unroll
                    for (int c = 1; c < CC; ++c) m = fmaxf(m, acc[c]);
                    float se = 0.f;
#pragma unroll
                    for (int c = 0; c < CC; ++c) se += expf(acc[c] - m);
                    float lse = m + logf(se);
#pragma unroll
                    for (int c = 0; c < CC; ++c) out[(size_t)g * CC + c] = acc[c] - lse;
                }
            }
        }
    } else {
        int node = (bid - GG) * 4 + (threadIdx.x >> 6);
        if (node >= NN) return;
        agg_node<true>(node, Z, rowptr, csr, stats, gamma, beta, aggOut);
    }
}

// ---------------- fused: xb = bf16(x), pooled[g] = sum rows of g ----------------

__global__ __launch_bounds__(256) void cvt_pool_x(const float* __restrict__ x,
                                                  const int* __restrict__ gptr,
                                                  unsigned short* __restrict__ xb,
                                                  float* __restrict__ dst) {
    __shared__ float2 red[4][64];
    int g = blockIdx.x;
    int wave = threadIdx.x >> 6, lane = threadIdx.x & 63;
    float ax = 0.f, ay = 0.f;
    int beg = gptr[g], end = gptr[g + 1];
    for (int r = beg + wave; r < end; r += 4) {
        float2 v = ((const float2*)(x + (size_t)r * DD))[lane];
        ax += v.x; ay += v.y;
        ((unsigned int*)(xb + (size_t)r * DD))[lane] =
            (unsigned int)f2b(v.x) | ((unsigned int)f2b(v.y) << 16);
    }
    red[wave][lane] = make_float2(ax, ay);
    __syncthreads();
    if (threadIdx.x < 64) {
        float2 a = red[0][lane], b = red[1][lane], c = red[2][lane], d = red[3][lane];
        ((float2*)dst)[(size_t)g * 64 + lane] =
            make_float2(a.x + b.x + c.x + d.x, a.y + b.y + c.y + d.y);
    }
}

// ---------------- launch ----------------

extern "C" void kernel_launch(void* const* d_in, const int* in_sizes, int n_in,
                              void* d_out, int out_size, void* d_ws, size_t ws_size,
                              hipStream_t stream) {
    const float* x     = (const float*)d_in[0];
    const int*   ei    = (const int*)d_in[1];
    const int*   batch = (const int*)d_in[2];
    const float* Wc1   = (const float*)d_in[3];
    const float* bc1   = (const float*)d_in[4];
    const float* Wc2   = (const float*)d_in[5];
    const float* bc2   = (const float*)d_in[6];
    const float* g_mid = (const float*)d_in[7];
    const float* b_mid = (const float*)d_in[8];
    const float* g_out = (const float*)d_in[9];
    const float* b_out = (const float*)d_in[10];
    const float* fcW   = (const float*)d_in[11];
    const float* fcb   = (const float*)d_in[12];
    float* out = (float*)d_out;

    char* p = (char*)d_ws;
    unsigned short* xb   = (unsigned short*)p; p += (size_t)NN * DD * 2;
    unsigned short* aggb = (unsigned short*)p; p += (size_t)NN * DD * 2;
    unsigned short* z1b  = (unsigned short*)p; p += (size_t)NN * DD * 2;
    unsigned short* z2b  = (unsigned short*)p; p += (size_t)NN * DD * 2;
    unsigned short* WTb  = (unsigned short*)p; p += (size_t)8 * DD * DD * 2;
    float* pooled = (float*)p; p += (size_t)(LL + 1) * GG * DD * 4;
    float* statb  = (float*)p; p += 8 * 256 * 4;
    int* deg    = (int*)p; p += (size_t)NN * 4;   // contiguous with statb for joint memset
    int* rowptr = (int*)p; p += (size_t)(NN + 16) * 4;
    int* cursor = (int*)p; p += (size_t)NN * 4;
    int* csr    = (int*)p; p += (size_t)EE * 4;
    int* gptr   = (int*)p; p += (size_t)(GG + 16) * 4;
    int* bsum1  = (int*)p; p += 64 * 4;

    hipMemsetAsync(statb, 0, (size_t)(8 * 256) * 4 + (size_t)NN * 4, stream);

    const int* src = ei;
    const int* dst = ei + EE;

    setup_kernel<<<HB_BLOCKS + PW_BLOCKS + 3, 256, 0, stream>>>(
        dst, deg, Wc1, Wc2, WTb, batch, gptr);

    const int nb = (NN + 1023) / 1024;  // 49
    block_sums<<<nb, 256, 0, stream>>>(deg, bsum1, NN);
    scan_bsums<<<1, 256, 0, stream>>>(bsum1, nb);
    scan_final<<<nb, 256, 0, stream>>>(deg, bsum1, rowptr, cursor, NN);
    fill_csr<<<(EE + 255) / 256, 256, 0, stream>>>(src, dst, cursor, csr);
    cvt_pool_x<<<GG, 256, 0, stream>>>(x, gptr, xb, pooled);

    const int gemmGrid = (NN + 127) / 128;  // 391
    aggregate_x<<<AGG_BLOCKS, 256, 0, stream>>>(xb, rowptr, csr, aggb);
    for (int l = 0; l < LL; ++l) {
        gemm_mfma<<<gemmGrid, 256, 0, stream>>>(
            aggb, WTb + (size_t)l * DD * DD, bc1 + (size_t)l * DD,
            nullptr, nullptr, nullptr,
            z1b, statb + (size_t)(2 * l) * 256);
        gemm_mfma<<<gemmGrid, 256, 0, stream>>>(
            z1b, WTb + (size_t)(4 + l) * DD * DD, bc2 + (size_t)l * DD,
            statb + (size_t)(2 * l) * 256, g_mid + (size_t)l * DD, b_mid + (size_t)l * DD,
            z2b, statb + (size_t)(2 * l + 1) * 256);
        if (l < LL - 1) {
            post_layer<false><<<GG + AGG_BLOCKS, 256, 0, stream>>>(
                z2b, statb + (size_t)(2 * l + 1) * 256,
                g_out + (size_t)l * DD, b_out + (size_t)l * DD,
                gptr, rowptr, csr,
                pooled + (size_t)(l + 1) * GG * DD, aggb,
                nullptr, nullptr, nullptr, nullptr);
        } else {
            post_layer<true><<<GG, 256, 0, stream>>>(
                z2b, statb + (size_t)(2 * l + 1) * 256,
                g_out + (size_t)l * DD, b_out + (size_t)l * DD,
                gptr, rowptr, csr,
                pooled + (size_t)(l + 1) * GG * DD, nullptr,
                pooled, fcW, fcb, out);
        }
    }
}

// Round 6
// 373.756 us; speedup vs baseline: 3.8839x; 1.0868x over previous
//
#include <hip/hip_runtime.h>
#include <hip/hip_bf16.h>

#define NN 50000
#define EE 600000
#define DD 128
#define LL 4
#define CC 10
#define GG 512
#define BN_EPS 1e-5f
#define ELLW 72

#define EB_BLOCKS ((EE + 255) / 256)          // 2344
#define PW_BLOCKS ((8 * DD * DD) / 256)       // 512
#define AGG_BLOCKS ((NN + 3) / 4)             // 12500
#define ZERO_N (8 * 256 + NN)                 // statb(2048 dwords) + cursor(NN)
#define ZERO_BLOCKS ((ZERO_N + 255) / 256)

typedef __attribute__((ext_vector_type(8))) short short8;
typedef __attribute__((ext_vector_type(4))) float f32x4;

__device__ __forceinline__ unsigned short f2b(float f) {
    union { float f; unsigned int u; } v; v.f = f;
    unsigned int u = v.u;
    unsigned int r = (u + 0x7fffu + ((u >> 16) & 1u)) >> 16;
    return (unsigned short)r;
}
__device__ __forceinline__ float b2f(unsigned short h) {
    union { unsigned int u; float f; } v; v.u = ((unsigned int)h) << 16;
    return v.f;
}

// ---------------- zero statb + cursor (replaces pathological hipMemsetAsync) ----------------

__global__ __launch_bounds__(256) void zero_kernel(int* __restrict__ base) {
    int i = blockIdx.x * 256 + threadIdx.x;
    if (i < ZERO_N) base[i] = 0;
}

// ---------------- setup: ELL fill + prep_weights + gptr_search in one dispatch ----------------

__global__ __launch_bounds__(256) void setup_kernel(const int* __restrict__ src,
                                                    const int* __restrict__ dst,
                                                    int* __restrict__ cursor,
                                                    int* __restrict__ ell,
                                                    const float* __restrict__ Wc1,
                                                    const float* __restrict__ Wc2,
                                                    unsigned short* __restrict__ WTb,
                                                    const int* __restrict__ batch,
                                                    int* __restrict__ gptr) {
    int b = blockIdx.x;
    if (b < EB_BLOCKS) {
        int e = b * 256 + threadIdx.x;
        if (e < EE) {
            int d = dst[e];
            int slot = atomicAdd(&cursor[d], 1);
            if (slot < ELLW) ell[(size_t)d * ELLW + slot] = src[e];
        }
    } else if (b < EB_BLOCKS + PW_BLOCKS) {
        int idx = (b - EB_BLOCKS) * 256 + threadIdx.x;   // 131072 total
        int mat = idx >> 14;
        int n = (idx >> 7) & 127;
        int k = idx & 127;
        const float* srcp = (mat < 4) ? (Wc1 + (size_t)mat * DD * DD)
                                      : (Wc2 + (size_t)(mat - 4) * DD * DD);
        WTb[idx] = f2b(srcp[k * DD + n]);
    } else {
        int g = (b - EB_BLOCKS - PW_BLOCKS) * 256 + threadIdx.x;
        if (g > GG) return;
        int lo = 0, hi = NN;
        while (lo < hi) {
            int mid = (lo + hi) >> 1;
            if (batch[mid] < g) lo = mid + 1; else hi = mid;
        }
        gptr[g] = lo;
    }
}

// ---------------- aggregation body (ELL edges) ----------------
// out[n] = t(h[n]) + sum_{src} t(h[src]),  t = BN-affine+ReLU if BN else identity.
// One wave per node: slot = lane>>4 (edge slot), seg = lane&15 (16B column segment).

template <bool BN>
__device__ __forceinline__ void agg_node(int node, const unsigned short* __restrict__ hb,
                                         const int* __restrict__ ell,
                                         const int* __restrict__ degA,
                                         const float* __restrict__ stats,
                                         const float* __restrict__ gamma,
                                         const float* __restrict__ beta,
                                         unsigned short* __restrict__ outb) {
    const int lane = threadIdx.x & 63;
    const int seg = lane & 15;
    const int slot = lane >> 4;

    float A[8], B[8];
    if (BN) {
#pragma unroll
        for (int j = 0; j < 8; ++j) {
            int c = seg * 8 + j;
            float mu = stats[c] * (1.0f / NN);
            float var = stats[DD + c] * (1.0f / NN) - mu * mu;
            A[j] = gamma[c] * rsqrtf(var + BN_EPS);
            B[j] = beta[c] - mu * A[j];
        }
    }

    const uint4* hb4 = (const uint4*)hb;            // row stride = 16 uint4
    uint4 self = hb4[(size_t)node * 16 + seg];

    float acc[8];
#pragma unroll
    for (int j = 0; j < 8; ++j) acc[j] = 0.f;

    const int* row = ell + (size_t)node * ELLW;
    const int dg = min(degA[node], ELLW);
    for (int e = 0; e < dg; e += 16) {
        int idx[4];
        bool val[4];
#pragma unroll
        for (int i = 0; i < 4; ++i) {
            int t = e + i * 4 + slot;
            val[i] = (t < dg);
            idx[i] = row[val[i] ? t : 0];
        }
        uint4 v[4];
#pragma unroll
        for (int i = 0; i < 4; ++i) v[i] = hb4[(size_t)idx[i] * 16 + seg];
#pragma unroll
        for (int i = 0; i < 4; ++i) {
            if (val[i]) {
#pragma unroll
                for (int j = 0; j < 4; ++j) {
                    unsigned int u = ((unsigned int*)&v[i])[j];
                    float x = b2f((unsigned short)(u & 0xffff));
                    float y = b2f((unsigned short)(u >> 16));
                    if (BN) {
                        x = fmaxf(0.f, fmaf(x, A[2 * j], B[2 * j]));
                        y = fmaxf(0.f, fmaf(y, A[2 * j + 1], B[2 * j + 1]));
                    }
                    acc[2 * j] += x;
                    acc[2 * j + 1] += y;
                }
            }
        }
    }

#pragma unroll
    for (int j = 0; j < 8; ++j) {
        acc[j] += __shfl_xor(acc[j], 16);
        acc[j] += __shfl_xor(acc[j], 32);
    }

    if (slot == 0) {
        uint4 o;
#pragma unroll
        for (int j = 0; j < 4; ++j) {
            unsigned int u = ((unsigned int*)&self)[j];
            float x = b2f((unsigned short)(u & 0xffff));
            float y = b2f((unsigned short)(u >> 16));
            if (BN) {
                x = fmaxf(0.f, fmaf(x, A[2 * j], B[2 * j]));
                y = fmaxf(0.f, fmaf(y, A[2 * j + 1], B[2 * j + 1]));
            }
            ((unsigned int*)&o)[j] =
                (unsigned int)f2b(acc[2 * j] + x) | ((unsigned int)f2b(acc[2 * j + 1] + y) << 16);
        }
        ((uint4*)outb)[(size_t)node * 16 + seg] = o;
    }
}

__global__ __launch_bounds__(256) void aggregate_x(const unsigned short* __restrict__ hb,
                                                   const int* __restrict__ ell,
                                                   const int* __restrict__ degA,
                                                   unsigned short* __restrict__ outb) {
    int node = blockIdx.x * 4 + (threadIdx.x >> 6);
    if (node >= NN) return;
    agg_node<false>(node, hb, ell, degA, nullptr, nullptr, nullptr, outb);
}

// ---------------- MFMA GEMM, W in registers: Out = (bn?)(Z) @ W + bias, + stats ----------------

__global__ __launch_bounds__(256, 2) void gemm_mfma(
    const unsigned short* __restrict__ Ab,   // [NN][128] bf16
    const unsigned short* __restrict__ WTb,  // [128][128] bf16 (WT[n][k])
    const float* __restrict__ bias,
    const float* __restrict__ bnStatsIn,     // null => raw input
    const float* __restrict__ gamma, const float* __restrict__ beta,
    unsigned short* __restrict__ Outb,       // [NN][128] bf16
    float* __restrict__ statsOut)            // [0..127]=colsum, [128..255]=colsumsq
{
    __shared__ unsigned short As[128 * 128];  // 32 KB, XOR-swizzled rows
    __shared__ float AbnS[DD], BbnS[DD];
    __shared__ float colred[2][DD];

    const int tid = threadIdx.x;
    const int row0 = blockIdx.x * 128;
    const bool doBn = (bnStatsIn != nullptr);
    const int lane = tid & 63;
    const int fr = lane & 15, fq = lane >> 4;

    // B fragments: all of W in registers (32 KB total, L2-hot). 8n x 4kk x 16B/lane.
    short8 bfrag[8][4];
#pragma unroll
    for (int n = 0; n < 8; ++n)
#pragma unroll
        for (int kk = 0; kk < 4; ++kk)
            bfrag[n][kk] = *(const short8*)((const char*)WTb + (n * 16 + fr) * 256 + kk * 64 + fq * 16);

    if (tid < DD) {
        colred[0][tid] = 0.f;
        colred[1][tid] = 0.f;
        if (doBn) {
            float mu = bnStatsIn[tid] * (1.0f / NN);
            float var = bnStatsIn[DD + tid] * (1.0f / NN) - mu * mu;
            float A = gamma[tid] * rsqrtf(var + BN_EPS);
            AbnS[tid] = A;
            BbnS[tid] = beta[tid] - mu * A;
        }
    }
    if (doBn) __syncthreads();

    // stage A tile (optional BN+ReLU on load)
#pragma unroll
    for (int i = 0; i < 8; ++i) {
        int c = tid + i * 256;
        int row = c >> 4, seg = c & 15;
        int gr = row0 + row;
        uint4 v = make_uint4(0u, 0u, 0u, 0u);
        if (gr < NN) v = ((const uint4*)(Ab + (size_t)gr * DD))[seg];
        if (doBn) {
            int k0 = seg * 8;
#pragma unroll
            for (int e = 0; e < 4; ++e) {
                unsigned int u = ((unsigned int*)&v)[e];
                int cidx = k0 + 2 * e;
                float lo = fmaxf(0.f, fmaf(b2f((unsigned short)(u & 0xffff)), AbnS[cidx], BbnS[cidx]));
                float hi = fmaxf(0.f, fmaf(b2f((unsigned short)(u >> 16)), AbnS[cidx + 1], BbnS[cidx + 1]));
                ((unsigned int*)&v)[e] = (unsigned int)f2b(lo) | ((unsigned int)f2b(hi) << 16);
            }
        }
        int byte = (row * 256 + seg * 16) ^ ((row & 7) << 4);
        *(uint4*)((char*)As + byte) = v;
    }
    __syncthreads();

    const int wave = tid >> 6;
    const int wr0 = wave * 32;

    f32x4 acc[2][8];
#pragma unroll
    for (int m = 0; m < 2; ++m)
#pragma unroll
        for (int n = 0; n < 8; ++n) acc[m][n] = (f32x4)0.f;

#pragma unroll
    for (int kk = 0; kk < 4; ++kk) {
        int kbyte = kk * 64 + fq * 16;
        short8 a[2];
#pragma unroll
        for (int m = 0; m < 2; ++m) {
            int row = wr0 + m * 16 + fr;
            a[m] = *(const short8*)((const char*)As + ((row * 256 + kbyte) ^ ((row & 7) << 4)));
        }
#pragma unroll
        for (int m = 0; m < 2; ++m)
#pragma unroll
            for (int n = 0; n < 8; ++n)
                acc[m][n] = __builtin_amdgcn_mfma_f32_16x16x32_bf16(a[m], bfrag[n][kk], acc[m][n], 0, 0, 0);
    }

    float bias_n[8], s[8], q[8];
#pragma unroll
    for (int n = 0; n < 8; ++n) {
        bias_n[n] = bias[n * 16 + fr];
        s[n] = 0.f;
        q[n] = 0.f;
    }
#pragma unroll
    for (int m = 0; m < 2; ++m) {
        int rbase = row0 + wr0 + m * 16 + fq * 4;
#pragma unroll
        for (int j = 0; j < 4; ++j) {
            int gr = rbase + j;
            if (gr < NN) {
#pragma unroll
                for (int n = 0; n < 8; ++n) {
                    float o = acc[m][n][j] + bias_n[n];
                    Outb[(size_t)gr * DD + n * 16 + fr] = f2b(o);
                    s[n] += o;
                    q[n] += o * o;
                }
            }
        }
    }
#pragma unroll
    for (int n = 0; n < 8; ++n) {
        s[n] += __shfl_xor(s[n], 16);
        s[n] += __shfl_xor(s[n], 32);
        q[n] += __shfl_xor(q[n], 16);
        q[n] += __shfl_xor(q[n], 32);
    }
    if (fq == 0) {
#pragma unroll
        for (int n = 0; n < 8; ++n) {
            atomicAdd(&colred[0][n * 16 + fr], s[n]);
            atomicAdd(&colred[1][n * 16 + fr], q[n]);
        }
    }
    __syncthreads();
    if (tid < DD) {
        atomicAdd(&statsOut[tid], colred[0][tid]);
        atomicAdd(&statsOut[DD + tid], colred[1][tid]);
    }
}

// ---------------- post_layer: bn_pool (blocks < GG) + next-layer aggregate (rest) ----------------
// LAST: pool blocks also compute the classifier + log_softmax for their graph.

template <bool LAST>
__global__ __launch_bounds__(256) void post_layer(
    const unsigned short* __restrict__ Z,      // z2b of this layer
    const float* __restrict__ stats,           // statb (2l+1)
    const float* __restrict__ gamma,           // g_out[l]
    const float* __restrict__ beta,            // b_out[l]
    const int* __restrict__ gptr,
    const int* __restrict__ ell,
    const int* __restrict__ degA,
    float* __restrict__ pooledDst,             // pooled + (l+1)*GG*DD
    unsigned short* __restrict__ aggOut,       // aggb for next layer (unused if LAST)
    const float* __restrict__ pooledAll,       // pooled base (LAST only)
    const float* __restrict__ fcW,
    const float* __restrict__ fcb,
    float* __restrict__ out)
{
    const int bid = blockIdx.x;
    if (bid < GG) {
        __shared__ float2 red[4][64];
        __shared__ float p4[DD];
        const int g = bid;
        const int wave = threadIdx.x >> 6, lane = threadIdx.x & 63;
        const int c0 = lane * 2, c1 = c0 + 1;
        float mu0 = stats[c0] * (1.0f / NN);
        float var0 = stats[DD + c0] * (1.0f / NN) - mu0 * mu0;
        float A0 = gamma[c0] * rsqrtf(var0 + BN_EPS);
        float B0 = beta[c0] - mu0 * A0;
        float mu1 = stats[c1] * (1.0f / NN);
        float var1 = stats[DD + c1] * (1.0f / NN) - mu1 * mu1;
        float A1 = gamma[c1] * rsqrtf(var1 + BN_EPS);
        float B1 = beta[c1] - mu1 * A1;

        float ax = 0.f, ay = 0.f;
        int beg = gptr[g], end = gptr[g + 1];
        for (int r = beg + wave; r < end; r += 4) {
            unsigned int u = ((const unsigned int*)(Z + (size_t)r * DD))[lane];
            ax += fmaxf(0.f, fmaf(b2f((unsigned short)(u & 0xffff)), A0, B0));
            ay += fmaxf(0.f, fmaf(b2f((unsigned short)(u >> 16)), A1, B1));
        }
        red[wave][lane] = make_float2(ax, ay);
        __syncthreads();
        if (threadIdx.x < 64) {
            float2 a = red[0][lane], b = red[1][lane], c = red[2][lane], d = red[3][lane];
            float2 r2 = make_float2(a.x + b.x + c.x + d.x, a.y + b.y + c.y + d.y);
            ((float2*)pooledDst)[(size_t)g * 64 + lane] = r2;
            if (LAST) {
                p4[c0] = r2.x;
                p4[c1] = r2.y;
            }
        }
        if (LAST) {
            __syncthreads();
            if (threadIdx.x < 64) {
                float acc[CC];
#pragma unroll
                for (int c = 0; c < CC; ++c) acc[c] = 0.f;
                for (int i = 0; i < LL + 1; ++i) {
                    const float* Wf = fcW + (size_t)i * DD * CC;
                    for (int k = lane; k < DD; k += 64) {
                        float pv = (i == LL) ? p4[k] : pooledAll[((size_t)i * GG + g) * DD + k];
                        const float* wr = Wf + k * CC;
#pragma unroll
                        for (int c = 0; c < CC; ++c) acc[c] = fmaf(pv, wr[c], acc[c]);
                    }
                }
#pragma unroll
                for (int c = 0; c < CC; ++c)
                    for (int off = 32; off > 0; off >>= 1) acc[c] += __shfl_down(acc[c], off);
                if (lane == 0) {
#pragma unroll
                    for (int c = 0; c < CC; ++c) {
                        float b = 0.f;
                        for (int i = 0; i < LL + 1; ++i) b += fcb[i * CC + c];
                        acc[c] += b;
                    }
                    float m = acc[0];
#pragma unroll
                    for (int c = 1; c < CC; ++c) m = fmaxf(m, acc[c]);
                    float se = 0.f;
#pragma unroll
                    for (int c = 0; c < CC; ++c) se += expf(acc[c] - m);
                    float lse = m + logf(se);
#pragma unroll
                    for (int c = 0; c < CC; ++c) out[(size_t)g * CC + c] = acc[c] - lse;
                }
            }
        }
    } else {
        int node = (bid - GG) * 4 + (threadIdx.x >> 6);
        if (node >= NN) return;
        agg_node<true>(node, Z, ell, degA, stats, gamma, beta, aggOut);
    }
}

// ---------------- fused: xb = bf16(x), pooled[g] = sum rows of g ----------------

__global__ __launch_bounds__(256) void cvt_pool_x(const float* __restrict__ x,
                                                  const int* __restrict__ gptr,
                                                  unsigned short* __restrict__ xb,
                                                  float* __restrict__ dst) {
    __shared__ float2 red[4][64];
    int g = blockIdx.x;
    int wave = threadIdx.x >> 6, lane = threadIdx.x & 63;
    float ax = 0.f, ay = 0.f;
    int beg = gptr[g], end = gptr[g + 1];
    for (int r = beg + wave; r < end; r += 4) {
        float2 v = ((const float2*)(x + (size_t)r * DD))[lane];
        ax += v.x; ay += v.y;
        ((unsigned int*)(xb + (size_t)r * DD))[lane] =
            (unsigned int)f2b(v.x) | ((unsigned int)f2b(v.y) << 16);
    }
    red[wave][lane] = make_float2(ax, ay);
    __syncthreads();
    if (threadIdx.x < 64) {
        float2 a = red[0][lane], b = red[1][lane], c = red[2][lane], d = red[3][lane];
        ((float2*)dst)[(size_t)g * 64 + lane] =
            make_float2(a.x + b.x + c.x + d.x, a.y + b.y + c.y + d.y);
    }
}

// ---------------- launch ----------------

extern "C" void kernel_launch(void* const* d_in, const int* in_sizes, int n_in,
                              void* d_out, int out_size, void* d_ws, size_t ws_size,
                              hipStream_t stream) {
    const float* x     = (const float*)d_in[0];
    const int*   ei    = (const int*)d_in[1];
    const int*   batch = (const int*)d_in[2];
    const float* Wc1   = (const float*)d_in[3];
    const float* bc1   = (const float*)d_in[4];
    const float* Wc2   = (const float*)d_in[5];
    const float* bc2   = (const float*)d_in[6];
    const float* g_mid = (const float*)d_in[7];
    const float* b_mid = (const float*)d_in[8];
    const float* g_out = (const float*)d_in[9];
    const float* b_out = (const float*)d_in[10];
    const float* fcW   = (const float*)d_in[11];
    const float* fcb   = (const float*)d_in[12];
    float* out = (float*)d_out;

    char* p = (char*)d_ws;
    unsigned short* xb   = (unsigned short*)p; p += (size_t)NN * DD * 2;
    unsigned short* aggb = (unsigned short*)p; p += (size_t)NN * DD * 2;
    unsigned short* z1b  = (unsigned short*)p; p += (size_t)NN * DD * 2;
    unsigned short* z2b  = (unsigned short*)p; p += (size_t)NN * DD * 2;
    unsigned short* WTb  = (unsigned short*)p; p += (size_t)8 * DD * DD * 2;
    float* pooled = (float*)p; p += (size_t)(LL + 1) * GG * DD * 4;
    float* statb  = (float*)p; p += 8 * 256 * 4;   // contiguous with cursor: joint zero
    int* cursor = (int*)p; p += (size_t)NN * 4;
    int* ell    = (int*)p; p += (size_t)NN * ELLW * 4;
    int* gptr   = (int*)p; p += (size_t)(GG + 16) * 4;

    const int* src = ei;
    const int* dst = ei + EE;

    zero_kernel<<<ZERO_BLOCKS, 256, 0, stream>>>((int*)statb);
    setup_kernel<<<EB_BLOCKS + PW_BLOCKS + 3, 256, 0, stream>>>(
        src, dst, cursor, ell, Wc1, Wc2, WTb, batch, gptr);
    cvt_pool_x<<<GG, 256, 0, stream>>>(x, gptr, xb, pooled);

    const int gemmGrid = (NN + 127) / 128;  // 391
    aggregate_x<<<AGG_BLOCKS, 256, 0, stream>>>(xb, ell, cursor, aggb);
    for (int l = 0; l < LL; ++l) {
        gemm_mfma<<<gemmGrid, 256, 0, stream>>>(
            aggb, WTb + (size_t)l * DD * DD, bc1 + (size_t)l * DD,
            nullptr, nullptr, nullptr,
            z1b, statb + (size_t)(2 * l) * 256);
        gemm_mfma<<<gemmGrid, 256, 0, stream>>>(
            z1b, WTb + (size_t)(4 + l) * DD * DD, bc2 + (size_t)l * DD,
            statb + (size_t)(2 * l) * 256, g_mid + (size_t)l * DD, b_mid + (size_t)l * DD,
            z2b, statb + (size_t)(2 * l + 1) * 256);
        if (l < LL - 1) {
            post_layer<false><<<GG + AGG_BLOCKS, 256, 0, stream>>>(
                z2b, statb + (size_t)(2 * l + 1) * 256,
                g_out + (size_t)l * DD, b_out + (size_t)l * DD,
                gptr, ell, cursor,
                pooled + (size_t)(l + 1) * GG * DD, aggb,
                nullptr, nullptr, nullptr, nullptr);
        } else {
            post_layer<true><<<GG, 256, 0, stream>>>(
                z2b, statb + (size_t)(2 * l + 1) * 256,
                g_out + (size_t)l * DD, b_out + (size_t)l * DD,
                gptr, ell, cursor,
                pooled + (size_t)(l + 1) * GG * DD, nullptr,
                pooled, fcW, fcb, out);
        }
    }
}

// Round 7
// 371.441 us; speedup vs baseline: 3.9081x; 1.0062x over previous
//
#include <hip/hip_runtime.h>
#include <hip/hip_bf16.h>

#define NN 50000
#define EE 600000
#define DD 128
#define LL 4
#define CC 10
#define GG 512
#define BN_EPS 1e-5f
#define ELLW 48

#define EB_BLOCKS ((EE + 255) / 256)          // 2344
#define PW_BLOCKS ((8 * DD * DD) / 256)       // 512
#define GP_BLOCKS 3
#define AGG_BLOCKS ((NN + 3) / 4)             // 12500
#define ZERO_N (8 * 256 + NN)                 // statb(2048 dwords) + cursor(NN)
#define ZERO_BLOCKS ((ZERO_N + 255) / 256)

typedef __attribute__((ext_vector_type(8))) short short8;
typedef __attribute__((ext_vector_type(4))) float f32x4;

__device__ __forceinline__ unsigned short f2b(float f) {
    union { float f; unsigned int u; } v; v.f = f;
    unsigned int u = v.u;
    unsigned int r = (u + 0x7fffu + ((u >> 16) & 1u)) >> 16;
    return (unsigned short)r;
}
__device__ __forceinline__ float b2f(unsigned short h) {
    union { unsigned int u; float f; } v; v.u = ((unsigned int)h) << 16;
    return v.f;
}

// ---------------- zero statb + cursor ----------------

__global__ __launch_bounds__(256) void zero_kernel(int* __restrict__ base) {
    int i = blockIdx.x * 256 + threadIdx.x;
    if (i < ZERO_N) base[i] = 0;
}

// ---------------- setup: ELL fill + prep_weights + gptr + cvt/pool of x ----------------

__global__ __launch_bounds__(256) void setup_kernel(const int* __restrict__ src,
                                                    const int* __restrict__ dst,
                                                    int* __restrict__ cursor,
                                                    unsigned short* __restrict__ ell,
                                                    const float* __restrict__ Wc1,
                                                    const float* __restrict__ Wc2,
                                                    unsigned short* __restrict__ WTb,
                                                    const int* __restrict__ batch,
                                                    int* __restrict__ gptr,
                                                    const float* __restrict__ x,
                                                    unsigned short* __restrict__ xb,
                                                    float* __restrict__ pooled0) {
    int b = blockIdx.x;
    if (b < EB_BLOCKS) {
        int e = b * 256 + threadIdx.x;
        if (e < EE) {
            int d = dst[e];
            int slot = atomicAdd(&cursor[d], 1);
            if (slot < ELLW) ell[(size_t)d * ELLW + slot] = (unsigned short)src[e];
        }
    } else if (b < EB_BLOCKS + PW_BLOCKS) {
        int idx = (b - EB_BLOCKS) * 256 + threadIdx.x;   // 131072 total
        int mat = idx >> 14;
        int n = (idx >> 7) & 127;
        int k = idx & 127;
        const float* srcp = (mat < 4) ? (Wc1 + (size_t)mat * DD * DD)
                                      : (Wc2 + (size_t)(mat - 4) * DD * DD);
        WTb[idx] = f2b(srcp[k * DD + n]);
    } else if (b < EB_BLOCKS + PW_BLOCKS + GP_BLOCKS) {
        int g = (b - EB_BLOCKS - PW_BLOCKS) * 256 + threadIdx.x;
        if (g > GG) return;
        int lo = 0, hi = NN;
        while (lo < hi) {
            int mid = (lo + hi) >> 1;
            if (batch[mid] < g) lo = mid + 1; else hi = mid;
        }
        gptr[g] = lo;
    } else {
        // one block per graph: bf16-convert rows + pool raw x
        __shared__ float2 red[4][64];
        const int g = b - EB_BLOCKS - PW_BLOCKS - GP_BLOCKS;
        int lo = 0, hi = NN;
        while (lo < hi) { int mid = (lo + hi) >> 1; if (batch[mid] < g) lo = mid + 1; else hi = mid; }
        int beg = lo;
        hi = NN;
        while (lo < hi) { int mid = (lo + hi) >> 1; if (batch[mid] < g + 1) lo = mid + 1; else hi = mid; }
        int end = lo;
        int wave = threadIdx.x >> 6, lane = threadIdx.x & 63;
        float ax = 0.f, ay = 0.f;
        for (int r = beg + wave; r < end; r += 4) {
            float2 v = ((const float2*)(x + (size_t)r * DD))[lane];
            ax += v.x; ay += v.y;
            ((unsigned int*)(xb + (size_t)r * DD))[lane] =
                (unsigned int)f2b(v.x) | ((unsigned int)f2b(v.y) << 16);
        }
        red[wave][lane] = make_float2(ax, ay);
        __syncthreads();
        if (threadIdx.x < 64) {
            float2 a = red[0][lane], bb = red[1][lane], c = red[2][lane], d = red[3][lane];
            ((float2*)pooled0)[(size_t)g * 64 + lane] =
                make_float2(a.x + bb.x + c.x + d.x, a.y + bb.y + c.y + d.y);
        }
    }
}

// ---------------- aggregation body (ushort ELL edges) ----------------
// out[n] = t(h[n]) + sum_{src} t(h[src]),  t = BN-affine+ReLU if BN else identity.
// One wave per node: slot = lane>>4 (edge slot), seg = lane&15 (16B column segment).

template <bool BN>
__device__ __forceinline__ void agg_node(int node, const unsigned short* __restrict__ hb,
                                         const unsigned short* __restrict__ ell,
                                         const int* __restrict__ degA,
                                         const float* __restrict__ stats,
                                         const float* __restrict__ gamma,
                                         const float* __restrict__ beta,
                                         unsigned short* __restrict__ outb) {
    const int lane = threadIdx.x & 63;
    const int seg = lane & 15;
    const int slot = lane >> 4;

    float A[8], B[8];
    if (BN) {
#pragma unroll
        for (int j = 0; j < 8; ++j) {
            int c = seg * 8 + j;
            float mu = stats[c] * (1.0f / NN);
            float var = stats[DD + c] * (1.0f / NN) - mu * mu;
            A[j] = gamma[c] * rsqrtf(var + BN_EPS);
            B[j] = beta[c] - mu * A[j];
        }
    }

    const uint4* hb4 = (const uint4*)hb;            // row stride = 16 uint4
    uint4 self = hb4[(size_t)node * 16 + seg];

    float acc[8];
#pragma unroll
    for (int j = 0; j < 8; ++j) acc[j] = 0.f;

    const unsigned short* row = ell + (size_t)node * ELLW;
    const int dg = min(degA[node], ELLW);
    for (int e = 0; e < dg; e += 16) {
        int idx[4];
        bool val[4];
#pragma unroll
        for (int i = 0; i < 4; ++i) {
            int t = e + i * 4 + slot;
            val[i] = (t < dg);
            idx[i] = row[val[i] ? t : 0];
        }
        uint4 v[4];
#pragma unroll
        for (int i = 0; i < 4; ++i) v[i] = hb4[(size_t)idx[i] * 16 + seg];
#pragma unroll
        for (int i = 0; i < 4; ++i) {
            if (val[i]) {
#pragma unroll
                for (int j = 0; j < 4; ++j) {
                    unsigned int u = ((unsigned int*)&v[i])[j];
                    float x = b2f((unsigned short)(u & 0xffff));
                    float y = b2f((unsigned short)(u >> 16));
                    if (BN) {
                        x = fmaxf(0.f, fmaf(x, A[2 * j], B[2 * j]));
                        y = fmaxf(0.f, fmaf(y, A[2 * j + 1], B[2 * j + 1]));
                    }
                    acc[2 * j] += x;
                    acc[2 * j + 1] += y;
                }
            }
        }
    }

#pragma unroll
    for (int j = 0; j < 8; ++j) {
        acc[j] += __shfl_xor(acc[j], 16);
        acc[j] += __shfl_xor(acc[j], 32);
    }

    if (slot == 0) {
        uint4 o;
#pragma unroll
        for (int j = 0; j < 4; ++j) {
            unsigned int u = ((unsigned int*)&self)[j];
            float x = b2f((unsigned short)(u & 0xffff));
            float y = b2f((unsigned short)(u >> 16));
            if (BN) {
                x = fmaxf(0.f, fmaf(x, A[2 * j], B[2 * j]));
                y = fmaxf(0.f, fmaf(y, A[2 * j + 1], B[2 * j + 1]));
            }
            ((unsigned int*)&o)[j] =
                (unsigned int)f2b(acc[2 * j] + x) | ((unsigned int)f2b(acc[2 * j + 1] + y) << 16);
        }
        ((uint4*)outb)[(size_t)node * 16 + seg] = o;
    }
}

__global__ __launch_bounds__(256) void aggregate_x(const unsigned short* __restrict__ hb,
                                                   const unsigned short* __restrict__ ell,
                                                   const int* __restrict__ degA,
                                                   unsigned short* __restrict__ outb) {
    int node = blockIdx.x * 4 + (threadIdx.x >> 6);
    if (node >= NN) return;
    agg_node<false>(node, hb, ell, degA, nullptr, nullptr, nullptr, outb);
}

// ---------------- MFMA GEMM, W in registers: Out = (bn?)(Z) @ W + bias, + stats ----------------

__global__ __launch_bounds__(256, 2) void gemm_mfma(
    const unsigned short* __restrict__ Ab,   // [NN][128] bf16
    const unsigned short* __restrict__ WTb,  // [128][128] bf16 (WT[n][k])
    const float* __restrict__ bias,
    const float* __restrict__ bnStatsIn,     // null => raw input
    const float* __restrict__ gamma, const float* __restrict__ beta,
    unsigned short* __restrict__ Outb,       // [NN][128] bf16
    float* __restrict__ statsOut)            // [0..127]=colsum, [128..255]=colsumsq
{
    __shared__ unsigned short As[128 * 128];  // 32 KB, XOR-swizzled rows
    __shared__ float AbnS[DD], BbnS[DD];
    __shared__ float colred[2][DD];

    const int tid = threadIdx.x;
    const int row0 = blockIdx.x * 128;
    const bool doBn = (bnStatsIn != nullptr);
    const int lane = tid & 63;
    const int fr = lane & 15, fq = lane >> 4;

    // B fragments: all of W in registers (32 KB total, L2-hot). 8n x 4kk x 16B/lane.
    short8 bfrag[8][4];
#pragma unroll
    for (int n = 0; n < 8; ++n)
#pragma unroll
        for (int kk = 0; kk < 4; ++kk)
            bfrag[n][kk] = *(const short8*)((const char*)WTb + (n * 16 + fr) * 256 + kk * 64 + fq * 16);

    if (tid < DD) {
        colred[0][tid] = 0.f;
        colred[1][tid] = 0.f;
        if (doBn) {
            float mu = bnStatsIn[tid] * (1.0f / NN);
            float var = bnStatsIn[DD + tid] * (1.0f / NN) - mu * mu;
            float A = gamma[tid] * rsqrtf(var + BN_EPS);
            AbnS[tid] = A;
            BbnS[tid] = beta[tid] - mu * A;
        }
    }
    if (doBn) __syncthreads();

    // stage A tile (optional BN+ReLU on load)
#pragma unroll
    for (int i = 0; i < 8; ++i) {
        int c = tid + i * 256;
        int row = c >> 4, seg = c & 15;
        int gr = row0 + row;
        uint4 v = make_uint4(0u, 0u, 0u, 0u);
        if (gr < NN) v = ((const uint4*)(Ab + (size_t)gr * DD))[seg];
        if (doBn) {
            int k0 = seg * 8;
#pragma unroll
            for (int e = 0; e < 4; ++e) {
                unsigned int u = ((unsigned int*)&v)[e];
                int cidx = k0 + 2 * e;
                float lo = fmaxf(0.f, fmaf(b2f((unsigned short)(u & 0xffff)), AbnS[cidx], BbnS[cidx]));
                float hi = fmaxf(0.f, fmaf(b2f((unsigned short)(u >> 16)), AbnS[cidx + 1], BbnS[cidx + 1]));
                ((unsigned int*)&v)[e] = (unsigned int)f2b(lo) | ((unsigned int)f2b(hi) << 16);
            }
        }
        int byte = (row * 256 + seg * 16) ^ ((row & 7) << 4);
        *(uint4*)((char*)As + byte) = v;
    }
    __syncthreads();

    const int wave = tid >> 6;
    const int wr0 = wave * 32;

    f32x4 acc[2][8];
#pragma unroll
    for (int m = 0; m < 2; ++m)
#pragma unroll
        for (int n = 0; n < 8; ++n) acc[m][n] = (f32x4)0.f;

#pragma unroll
    for (int kk = 0; kk < 4; ++kk) {
        int kbyte = kk * 64 + fq * 16;
        short8 a[2];
#pragma unroll
        for (int m = 0; m < 2; ++m) {
            int row = wr0 + m * 16 + fr;
            a[m] = *(const short8*)((const char*)As + ((row * 256 + kbyte) ^ ((row & 7) << 4)));
        }
#pragma unroll
        for (int m = 0; m < 2; ++m)
#pragma unroll
            for (int n = 0; n < 8; ++n)
                acc[m][n] = __builtin_amdgcn_mfma_f32_16x16x32_bf16(a[m], bfrag[n][kk], acc[m][n], 0, 0, 0);
    }

    float bias_n[8], s[8], q[8];
#pragma unroll
    for (int n = 0; n < 8; ++n) {
        bias_n[n] = bias[n * 16 + fr];
        s[n] = 0.f;
        q[n] = 0.f;
    }
#pragma unroll
    for (int m = 0; m < 2; ++m) {
        int rbase = row0 + wr0 + m * 16 + fq * 4;
#pragma unroll
        for (int j = 0; j < 4; ++j) {
            int gr = rbase + j;
            if (gr < NN) {
#pragma unroll
                for (int n = 0; n < 8; ++n) {
                    float o = acc[m][n][j] + bias_n[n];
                    Outb[(size_t)gr * DD + n * 16 + fr] = f2b(o);
                    s[n] += o;
                    q[n] += o * o;
                }
            }
        }
    }
#pragma unroll
    for (int n = 0; n < 8; ++n) {
        s[n] += __shfl_xor(s[n], 16);
        s[n] += __shfl_xor(s[n], 32);
        q[n] += __shfl_xor(q[n], 16);
        q[n] += __shfl_xor(q[n], 32);
    }
    if (fq == 0) {
#pragma unroll
        for (int n = 0; n < 8; ++n) {
            atomicAdd(&colred[0][n * 16 + fr], s[n]);
            atomicAdd(&colred[1][n * 16 + fr], q[n]);
        }
    }
    __syncthreads();
    if (tid < DD) {
        atomicAdd(&statsOut[tid], colred[0][tid]);
        atomicAdd(&statsOut[DD + tid], colred[1][tid]);
    }
}

// ---------------- post_layer: bn_pool (blocks < GG) + next-layer aggregate (rest) ----------------

template <bool LAST>
__global__ __launch_bounds__(256) void post_layer(
    const unsigned short* __restrict__ Z,      // z2b of this layer
    const float* __restrict__ stats,           // statb (2l+1)
    const float* __restrict__ gamma,           // g_out[l]
    const float* __restrict__ beta,            // b_out[l]
    const int* __restrict__ gptr,
    const unsigned short* __restrict__ ell,
    const int* __restrict__ degA,
    float* __restrict__ pooledDst,             // pooled + (l+1)*GG*DD
    unsigned short* __restrict__ aggOut,       // aggb for next layer (unused if LAST)
    const float* __restrict__ pooledAll,       // pooled base (LAST only)
    const float* __restrict__ fcW,
    const float* __restrict__ fcb,
    float* __restrict__ out)
{
    const int bid = blockIdx.x;
    if (bid < GG) {
        __shared__ float2 red[4][64];
        __shared__ float p4[DD];
        const int g = bid;
        const int wave = threadIdx.x >> 6, lane = threadIdx.x & 63;
        const int c0 = lane * 2, c1 = c0 + 1;
        float mu0 = stats[c0] * (1.0f / NN);
        float var0 = stats[DD + c0] * (1.0f / NN) - mu0 * mu0;
        float A0 = gamma[c0] * rsqrtf(var0 + BN_EPS);
        float B0 = beta[c0] - mu0 * A0;
        float mu1 = stats[c1] * (1.0f / NN);
        float var1 = stats[DD + c1] * (1.0f / NN) - mu1 * mu1;
        float A1 = gamma[c1] * rsqrtf(var1 + BN_EPS);
        float B1 = beta[c1] - mu1 * A1;

        float ax = 0.f, ay = 0.f;
        int beg = gptr[g], end = gptr[g + 1];
        for (int r = beg + wave; r < end; r += 4) {
            unsigned int u = ((const unsigned int*)(Z + (size_t)r * DD))[lane];
            ax += fmaxf(0.f, fmaf(b2f((unsigned short)(u & 0xffff)), A0, B0));
            ay += fmaxf(0.f, fmaf(b2f((unsigned short)(u >> 16)), A1, B1));
        }
        red[wave][lane] = make_float2(ax, ay);
        __syncthreads();
        if (threadIdx.x < 64) {
            float2 a = red[0][lane], b = red[1][lane], c = red[2][lane], d = red[3][lane];
            float2 r2 = make_float2(a.x + b.x + c.x + d.x, a.y + b.y + c.y + d.y);
            ((float2*)pooledDst)[(size_t)g * 64 + lane] = r2;
            if (LAST) {
                p4[c0] = r2.x;
                p4[c1] = r2.y;
            }
        }
        if (LAST) {
            __syncthreads();
            if (threadIdx.x < 64) {
                float acc[CC];
#pragma unroll
                for (int c = 0; c < CC; ++c) acc[c] = 0.f;
                for (int i = 0; i < LL + 1; ++i) {
                    const float* Wf = fcW + (size_t)i * DD * CC;
                    for (int k = lane; k < DD; k += 64) {
                        float pv = (i == LL) ? p4[k] : pooledAll[((size_t)i * GG + g) * DD + k];
                        const float* wr = Wf + k * CC;
#pragma unroll
                        for (int c = 0; c < CC; ++c) acc[c] = fmaf(pv, wr[c], acc[c]);
                    }
                }
#pragma unroll
                for (int c = 0; c < CC; ++c)
                    for (int off = 32; off > 0; off >>= 1) acc[c] += __shfl_down(acc[c], off);
                if (lane == 0) {
#pragma unroll
                    for (int c = 0; c < CC; ++c) {
                        float b = 0.f;
                        for (int i = 0; i < LL + 1; ++i) b += fcb[i * CC + c];
                        acc[c] += b;
                    }
                    float m = acc[0];
#pragma unroll
                    for (int c = 1; c < CC; ++c) m = fmaxf(m, acc[c]);
                    float se = 0.f;
#pragma unroll
                    for (int c = 0; c < CC; ++c) se += expf(acc[c] - m);
                    float lse = m + logf(se);
#pragma unroll
                    for (int c = 0; c < CC; ++c) out[(size_t)g * CC + c] = acc[c] - lse;
                }
            }
        }
    } else {
        int node = (bid - GG) * 4 + (threadIdx.x >> 6);
        if (node >= NN) return;
        agg_node<true>(node, Z, ell, degA, stats, gamma, beta, aggOut);
    }
}

// ---------------- launch ----------------

extern "C" void kernel_launch(void* const* d_in, const int* in_sizes, int n_in,
                              void* d_out, int out_size, void* d_ws, size_t ws_size,
                              hipStream_t stream) {
    const float* x     = (const float*)d_in[0];
    const int*   ei    = (const int*)d_in[1];
    const int*   batch = (const int*)d_in[2];
    const float* Wc1   = (const float*)d_in[3];
    const float* bc1   = (const float*)d_in[4];
    const float* Wc2   = (const float*)d_in[5];
    const float* bc2   = (const float*)d_in[6];
    const float* g_mid = (const float*)d_in[7];
    const float* b_mid = (const float*)d_in[8];
    const float* g_out = (const float*)d_in[9];
    const float* b_out = (const float*)d_in[10];
    const float* fcW   = (const float*)d_in[11];
    const float* fcb   = (const float*)d_in[12];
    float* out = (float*)d_out;

    char* p = (char*)d_ws;
    unsigned short* xb   = (unsigned short*)p; p += (size_t)NN * DD * 2;
    unsigned short* aggb = (unsigned short*)p; p += (size_t)NN * DD * 2;
    unsigned short* z1b  = (unsigned short*)p; p += (size_t)NN * DD * 2;
    unsigned short* z2b  = (unsigned short*)p; p += (size_t)NN * DD * 2;
    unsigned short* WTb  = (unsigned short*)p; p += (size_t)8 * DD * DD * 2;
    float* pooled = (float*)p; p += (size_t)(LL + 1) * GG * DD * 4;
    float* statb  = (float*)p; p += 8 * 256 * 4;   // contiguous with cursor: joint zero
    int* cursor = (int*)p; p += (size_t)NN * 4;
    unsigned short* ell = (unsigned short*)p; p += (size_t)NN * ELLW * 2;
    int* gptr   = (int*)p; p += (size_t)(GG + 16) * 4;

    const int* src = ei;
    const int* dst = ei + EE;

    zero_kernel<<<ZERO_BLOCKS, 256, 0, stream>>>((int*)statb);
    setup_kernel<<<EB_BLOCKS + PW_BLOCKS + GP_BLOCKS + GG, 256, 0, stream>>>(
        src, dst, cursor, ell, Wc1, Wc2, WTb, batch, gptr, x, xb, pooled);

    const int gemmGrid = (NN + 127) / 128;  // 391
    aggregate_x<<<AGG_BLOCKS, 256, 0, stream>>>(xb, ell, cursor, aggb);
    for (int l = 0; l < LL; ++l) {
        gemm_mfma<<<gemmGrid, 256, 0, stream>>>(
            aggb, WTb + (size_t)l * DD * DD, bc1 + (size_t)l * DD,
            nullptr, nullptr, nullptr,
            z1b, statb + (size_t)(2 * l) * 256);
        gemm_mfma<<<gemmGrid, 256, 0, stream>>>(
            z1b, WTb + (size_t)(4 + l) * DD * DD, bc2 + (size_t)l * DD,
            statb + (size_t)(2 * l) * 256, g_mid + (size_t)l * DD, b_mid + (size_t)l * DD,
            z2b, statb + (size_t)(2 * l + 1) * 256);
        if (l < LL - 1) {
            post_layer<false><<<GG + AGG_BLOCKS, 256, 0, stream>>>(
                z2b, statb + (size_t)(2 * l + 1) * 256,
                g_out + (size_t)l * DD, b_out + (size_t)l * DD,
                gptr, ell, cursor,
                pooled + (size_t)(l + 1) * GG * DD, aggb,
                nullptr, nullptr, nullptr, nullptr);
        } else {
            post_layer<true><<<GG, 256, 0, stream>>>(
                z2b, statb + (size_t)(2 * l + 1) * 256,
                g_out + (size_t)l * DD, b_out + (size_t)l * DD,
                gptr, ell, cursor,
                pooled + (size_t)(l + 1) * GG * DD, nullptr,
                pooled, fcW, fcb, out);
        }
    }
}

// Round 8
// 359.525 us; speedup vs baseline: 4.0376x; 1.0331x over previous
//
#include <hip/hip_runtime.h>
#include <hip/hip_bf16.h>

#define NN 50000
#define EE 600000
#define DD 128
#define LL 4
#define CC 10
#define GG 512
#define BN_EPS 1e-5f
#define ELLW 48

#define EB_BLOCKS ((EE + 255) / 256)          // 2344
#define PW_BLOCKS ((8 * DD * DD) / 256)       // 512
#define GP_BLOCKS 3
#define AGG_BLOCKS (NN / 8)                   // 6250 (2 nodes per wave, 4 waves)
#define ZERO_N (8 * 256 + NN)                 // statb(2048 dwords) + cursor(NN)
#define ZERO_BLOCKS ((ZERO_N + 255) / 256)

typedef __attribute__((ext_vector_type(8))) short short8;
typedef __attribute__((ext_vector_type(4))) float f32x4;

__device__ __forceinline__ unsigned short f2b(float f) {
    union { float f; unsigned int u; } v; v.f = f;
    unsigned int u = v.u;
    unsigned int r = (u + 0x7fffu + ((u >> 16) & 1u)) >> 16;
    return (unsigned short)r;
}
__device__ __forceinline__ float b2f(unsigned short h) {
    union { unsigned int u; float f; } v; v.u = ((unsigned int)h) << 16;
    return v.f;
}

// ---------------- zero statb + cursor ----------------

__global__ __launch_bounds__(256) void zero_kernel(int* __restrict__ base) {
    int i = blockIdx.x * 256 + threadIdx.x;
    if (i < ZERO_N) base[i] = 0;
}

// ---------------- setup: pool/cvt of x (first) + ELL fill + prep_weights + gptr ----------------

__global__ __launch_bounds__(256) void setup_kernel(const int* __restrict__ src,
                                                    const int* __restrict__ dst,
                                                    int* __restrict__ cursor,
                                                    int* __restrict__ ell,
                                                    const float* __restrict__ Wc1,
                                                    const float* __restrict__ Wc2,
                                                    unsigned short* __restrict__ WTb,
                                                    const int* __restrict__ batch,
                                                    int* __restrict__ gptr,
                                                    const float* __restrict__ x,
                                                    unsigned short* __restrict__ xb,
                                                    float* __restrict__ pooled0) {
    int b = blockIdx.x;
    if (b < GG) {
        // one block per graph: bf16-convert rows + pool raw x (launched first: streams HBM
        // while the edge-fill blocks wait on atomics)
        __shared__ float2 red[4][64];
        const int g = b;
        int lo = 0, hi = NN;
        while (lo < hi) { int mid = (lo + hi) >> 1; if (batch[mid] < g) lo = mid + 1; else hi = mid; }
        int beg = lo;
        hi = NN;
        while (lo < hi) { int mid = (lo + hi) >> 1; if (batch[mid] < g + 1) lo = mid + 1; else hi = mid; }
        int end = lo;
        int wave = threadIdx.x >> 6, lane = threadIdx.x & 63;
        float ax = 0.f, ay = 0.f;
        for (int r = beg + wave; r < end; r += 4) {
            float2 v = ((const float2*)(x + (size_t)r * DD))[lane];
            ax += v.x; ay += v.y;
            ((unsigned int*)(xb + (size_t)r * DD))[lane] =
                (unsigned int)f2b(v.x) | ((unsigned int)f2b(v.y) << 16);
        }
        red[wave][lane] = make_float2(ax, ay);
        __syncthreads();
        if (threadIdx.x < 64) {
            float2 a = red[0][lane], bb = red[1][lane], c = red[2][lane], d = red[3][lane];
            ((float2*)pooled0)[(size_t)g * 64 + lane] =
                make_float2(a.x + bb.x + c.x + d.x, a.y + bb.y + c.y + d.y);
        }
    } else if (b < GG + EB_BLOCKS) {
        int e = (b - GG) * 256 + threadIdx.x;
        if (e < EE) {
            int d = dst[e];
            int slot = atomicAdd(&cursor[d], 1);
            if (slot < ELLW) ell[(size_t)d * ELLW + slot] = src[e];
        }
    } else if (b < GG + EB_BLOCKS + PW_BLOCKS) {
        int idx = (b - GG - EB_BLOCKS) * 256 + threadIdx.x;   // 131072 total
        int mat = idx >> 14;
        int n = (idx >> 7) & 127;
        int k = idx & 127;
        const float* srcp = (mat < 4) ? (Wc1 + (size_t)mat * DD * DD)
                                      : (Wc2 + (size_t)(mat - 4) * DD * DD);
        WTb[idx] = f2b(srcp[k * DD + n]);
    } else {
        int g = (b - GG - EB_BLOCKS - PW_BLOCKS) * 256 + threadIdx.x;
        if (g > GG) return;
        int lo = 0, hi = NN;
        while (lo < hi) {
            int mid = (lo + hi) >> 1;
            if (batch[mid] < g) lo = mid + 1; else hi = mid;
        }
        gptr[g] = lo;
    }
}

// ---------------- aggregation: 2 nodes per wave, predicated gathers ----------------
// out[n] = t(h[n]) + sum_{src} t(h[src]),  t = BN-affine+ReLU if BN else identity.
// Wave layout: slot = lane>>4 (edge slot), seg = lane&15 (16B column segment).
// nA is even; the wave handles nodes nA and nA+1.

template <bool BN>
__device__ __forceinline__ void agg_pair(int nA, const unsigned short* __restrict__ hb,
                                         const int* __restrict__ ell,
                                         const int* __restrict__ degA,
                                         const float* __restrict__ stats,
                                         const float* __restrict__ gamma,
                                         const float* __restrict__ beta,
                                         unsigned short* __restrict__ outb) {
    const int lane = threadIdx.x & 63;
    const int seg = lane & 15;
    const int slot = lane >> 4;

    float A[8], B[8];
    if (BN) {
#pragma unroll
        for (int j = 0; j < 8; ++j) {
            int c = seg * 8 + j;
            float mu = stats[c] * (1.0f / NN);
            float var = stats[DD + c] * (1.0f / NN) - mu * mu;
            A[j] = gamma[c] * rsqrtf(var + BN_EPS);
            B[j] = beta[c] - mu * A[j];
        }
    }

    const uint4* hb4 = (const uint4*)hb;            // row stride = 16 uint4
    // lanes slot 0 need self of nA, slot 1 self of nA+1; slots 2,3 load nA (unused)
    uint4 self = hb4[(size_t)(nA + (slot == 1 ? 1 : 0)) * 16 + seg];

    float accA[8], accB[8];
#pragma unroll
    for (int j = 0; j < 8; ++j) { accA[j] = 0.f; accB[j] = 0.f; }

    const int* rowA = ell + (size_t)nA * ELLW;
    const int* rowB = rowA + ELLW;
    const int dgA = min(degA[nA], ELLW);
    const int dgB = min(degA[nA + 1], ELLW);
    const int dgM = max(dgA, dgB);

    for (int e = 0; e < dgM; e += 16) {
        bool vA[4], vB[4];
        int iA[4], iB[4];
#pragma unroll
        for (int i = 0; i < 4; ++i) {
            int t = e + i * 4 + slot;
            vA[i] = (t < dgA);
            vB[i] = (t < dgB);
            iA[i] = rowA[t];   // in-bounds (<= ELLW-1); value unused when !vA
            iB[i] = rowB[t];
        }
        uint4 a[4], b[4];
#pragma unroll
        for (int i = 0; i < 4; ++i) {
            if (vA[i]) a[i] = hb4[(size_t)iA[i] * 16 + seg];
        }
#pragma unroll
        for (int i = 0; i < 4; ++i) {
            if (vB[i]) b[i] = hb4[(size_t)iB[i] * 16 + seg];
        }
#pragma unroll
        for (int i = 0; i < 4; ++i) {
            if (vA[i]) {
#pragma unroll
                for (int j = 0; j < 4; ++j) {
                    unsigned int u = ((unsigned int*)&a[i])[j];
                    float x = b2f((unsigned short)(u & 0xffff));
                    float y = b2f((unsigned short)(u >> 16));
                    if (BN) {
                        x = fmaxf(0.f, fmaf(x, A[2 * j], B[2 * j]));
                        y = fmaxf(0.f, fmaf(y, A[2 * j + 1], B[2 * j + 1]));
                    }
                    accA[2 * j] += x;
                    accA[2 * j + 1] += y;
                }
            }
            if (vB[i]) {
#pragma unroll
                for (int j = 0; j < 4; ++j) {
                    unsigned int u = ((unsigned int*)&b[i])[j];
                    float x = b2f((unsigned short)(u & 0xffff));
                    float y = b2f((unsigned short)(u >> 16));
                    if (BN) {
                        x = fmaxf(0.f, fmaf(x, A[2 * j], B[2 * j]));
                        y = fmaxf(0.f, fmaf(y, A[2 * j + 1], B[2 * j + 1]));
                    }
                    accB[2 * j] += x;
                    accB[2 * j + 1] += y;
                }
            }
        }
    }

#pragma unroll
    for (int j = 0; j < 8; ++j) {
        accA[j] += __shfl_xor(accA[j], 16);
        accA[j] += __shfl_xor(accA[j], 32);
        accB[j] += __shfl_xor(accB[j], 16);
        accB[j] += __shfl_xor(accB[j], 32);
    }

    if (slot < 2) {
        uint4 o;
#pragma unroll
        for (int j = 0; j < 4; ++j) {
            unsigned int u = ((unsigned int*)&self)[j];
            float x = b2f((unsigned short)(u & 0xffff));
            float y = b2f((unsigned short)(u >> 16));
            if (BN) {
                x = fmaxf(0.f, fmaf(x, A[2 * j], B[2 * j]));
                y = fmaxf(0.f, fmaf(y, A[2 * j + 1], B[2 * j + 1]));
            }
            float sx = (slot == 0) ? accA[2 * j] : accB[2 * j];
            float sy = (slot == 0) ? accA[2 * j + 1] : accB[2 * j + 1];
            ((unsigned int*)&o)[j] =
                (unsigned int)f2b(sx + x) | ((unsigned int)f2b(sy + y) << 16);
        }
        ((uint4*)outb)[(size_t)(nA + slot) * 16 + seg] = o;
    }
}

__global__ __launch_bounds__(256) void aggregate_x(const unsigned short* __restrict__ hb,
                                                   const int* __restrict__ ell,
                                                   const int* __restrict__ degA,
                                                   unsigned short* __restrict__ outb) {
    int nA = blockIdx.x * 8 + (threadIdx.x >> 6) * 2;   // NN % 8 == 0: no bounds check
    agg_pair<false>(nA, hb, ell, degA, nullptr, nullptr, nullptr, outb);
}

// ---------------- MFMA GEMM, W in registers: Out = (bn?)(Z) @ W + bias, + stats ----------------

__global__ __launch_bounds__(256, 2) void gemm_mfma(
    const unsigned short* __restrict__ Ab,   // [NN][128] bf16
    const unsigned short* __restrict__ WTb,  // [128][128] bf16 (WT[n][k])
    const float* __restrict__ bias,
    const float* __restrict__ bnStatsIn,     // null => raw input
    const float* __restrict__ gamma, const float* __restrict__ beta,
    unsigned short* __restrict__ Outb,       // [NN][128] bf16
    float* __restrict__ statsOut)            // [0..127]=colsum, [128..255]=colsumsq
{
    __shared__ unsigned short As[128 * 128];  // 32 KB, XOR-swizzled rows
    __shared__ float AbnS[DD], BbnS[DD];
    __shared__ float colred[2][DD];

    const int tid = threadIdx.x;
    const int row0 = blockIdx.x * 128;
    const bool doBn = (bnStatsIn != nullptr);
    const int lane = tid & 63;
    const int fr = lane & 15, fq = lane >> 4;

    // B fragments: all of W in registers (32 KB total, L2-hot). 8n x 4kk x 16B/lane.
    short8 bfrag[8][4];
#pragma unroll
    for (int n = 0; n < 8; ++n)
#pragma unroll
        for (int kk = 0; kk < 4; ++kk)
            bfrag[n][kk] = *(const short8*)((const char*)WTb + (n * 16 + fr) * 256 + kk * 64 + fq * 16);

    if (tid < DD) {
        colred[0][tid] = 0.f;
        colred[1][tid] = 0.f;
        if (doBn) {
            float mu = bnStatsIn[tid] * (1.0f / NN);
            float var = bnStatsIn[DD + tid] * (1.0f / NN) - mu * mu;
            float A = gamma[tid] * rsqrtf(var + BN_EPS);
            AbnS[tid] = A;
            BbnS[tid] = beta[tid] - mu * A;
        }
    }
    if (doBn) __syncthreads();

    // stage A tile (optional BN+ReLU on load)
#pragma unroll
    for (int i = 0; i < 8; ++i) {
        int c = tid + i * 256;
        int row = c >> 4, seg = c & 15;
        int gr = row0 + row;
        uint4 v = make_uint4(0u, 0u, 0u, 0u);
        if (gr < NN) v = ((const uint4*)(Ab + (size_t)gr * DD))[seg];
        if (doBn) {
            int k0 = seg * 8;
#pragma unroll
            for (int e = 0; e < 4; ++e) {
                unsigned int u = ((unsigned int*)&v)[e];
                int cidx = k0 + 2 * e;
                float lo = fmaxf(0.f, fmaf(b2f((unsigned short)(u & 0xffff)), AbnS[cidx], BbnS[cidx]));
                float hi = fmaxf(0.f, fmaf(b2f((unsigned short)(u >> 16)), AbnS[cidx + 1], BbnS[cidx + 1]));
                ((unsigned int*)&v)[e] = (unsigned int)f2b(lo) | ((unsigned int)f2b(hi) << 16);
            }
        }
        int byte = (row * 256 + seg * 16) ^ ((row & 7) << 4);
        *(uint4*)((char*)As + byte) = v;
    }
    __syncthreads();

    const int wave = tid >> 6;
    const int wr0 = wave * 32;

    f32x4 acc[2][8];
#pragma unroll
    for (int m = 0; m < 2; ++m)
#pragma unroll
        for (int n = 0; n < 8; ++n) acc[m][n] = (f32x4)0.f;

#pragma unroll
    for (int kk = 0; kk < 4; ++kk) {
        int kbyte = kk * 64 + fq * 16;
        short8 a[2];
#pragma unroll
        for (int m = 0; m < 2; ++m) {
            int row = wr0 + m * 16 + fr;
            a[m] = *(const short8*)((const char*)As + ((row * 256 + kbyte) ^ ((row & 7) << 4)));
        }
#pragma unroll
        for (int m = 0; m < 2; ++m)
#pragma unroll
            for (int n = 0; n < 8; ++n)
                acc[m][n] = __builtin_amdgcn_mfma_f32_16x16x32_bf16(a[m], bfrag[n][kk], acc[m][n], 0, 0, 0);
    }

    float bias_n[8], s[8], q[8];
#pragma unroll
    for (int n = 0; n < 8; ++n) {
        bias_n[n] = bias[n * 16 + fr];
        s[n] = 0.f;
        q[n] = 0.f;
    }
#pragma unroll
    for (int m = 0; m < 2; ++m) {
        int rbase = row0 + wr0 + m * 16 + fq * 4;
#pragma unroll
        for (int j = 0; j < 4; ++j) {
            int gr = rbase + j;
            if (gr < NN) {
#pragma unroll
                for (int n = 0; n < 8; ++n) {
                    float o = acc[m][n][j] + bias_n[n];
                    Outb[(size_t)gr * DD + n * 16 + fr] = f2b(o);
                    s[n] += o;
                    q[n] += o * o;
                }
            }
        }
    }
#pragma unroll
    for (int n = 0; n < 8; ++n) {
        s[n] += __shfl_xor(s[n], 16);
        s[n] += __shfl_xor(s[n], 32);
        q[n] += __shfl_xor(q[n], 16);
        q[n] += __shfl_xor(q[n], 32);
    }
    if (fq == 0) {
#pragma unroll
        for (int n = 0; n < 8; ++n) {
            atomicAdd(&colred[0][n * 16 + fr], s[n]);
            atomicAdd(&colred[1][n * 16 + fr], q[n]);
        }
    }
    __syncthreads();
    if (tid < DD) {
        atomicAdd(&statsOut[tid], colred[0][tid]);
        atomicAdd(&statsOut[DD + tid], colred[1][tid]);
    }
}

// ---------------- post_layer: bn_pool (blocks < GG) + next-layer aggregate (rest) ----------------

template <bool LAST>
__global__ __launch_bounds__(256) void post_layer(
    const unsigned short* __restrict__ Z,      // z2b of this layer
    const float* __restrict__ stats,           // statb (2l+1)
    const float* __restrict__ gamma,           // g_out[l]
    const float* __restrict__ beta,            // b_out[l]
    const int* __restrict__ gptr,
    const int* __restrict__ ell,
    const int* __restrict__ degA,
    float* __restrict__ pooledDst,             // pooled + (l+1)*GG*DD
    unsigned short* __restrict__ aggOut,       // aggb for next layer (unused if LAST)
    const float* __restrict__ pooledAll,       // pooled base (LAST only)
    const float* __restrict__ fcW,
    const float* __restrict__ fcb,
    float* __restrict__ out)
{
    const int bid = blockIdx.x;
    if (bid < GG) {
        __shared__ float2 red[4][64];
        __shared__ float p4[DD];
        const int g = bid;
        const int wave = threadIdx.x >> 6, lane = threadIdx.x & 63;
        const int c0 = lane * 2, c1 = c0 + 1;
        float mu0 = stats[c0] * (1.0f / NN);
        float var0 = stats[DD + c0] * (1.0f / NN) - mu0 * mu0;
        float A0 = gamma[c0] * rsqrtf(var0 + BN_EPS);
        float B0 = beta[c0] - mu0 * A0;
        float mu1 = stats[c1] * (1.0f / NN);
        float var1 = stats[DD + c1] * (1.0f / NN) - mu1 * mu1;
        float A1 = gamma[c1] * rsqrtf(var1 + BN_EPS);
        float B1 = beta[c1] - mu1 * A1;

        float ax = 0.f, ay = 0.f;
        int beg = gptr[g], end = gptr[g + 1];
        for (int r = beg + wave; r < end; r += 4) {
            unsigned int u = ((const unsigned int*)(Z + (size_t)r * DD))[lane];
            ax += fmaxf(0.f, fmaf(b2f((unsigned short)(u & 0xffff)), A0, B0));
            ay += fmaxf(0.f, fmaf(b2f((unsigned short)(u >> 16)), A1, B1));
        }
        red[wave][lane] = make_float2(ax, ay);
        __syncthreads();
        if (threadIdx.x < 64) {
            float2 a = red[0][lane], b = red[1][lane], c = red[2][lane], d = red[3][lane];
            float2 r2 = make_float2(a.x + b.x + c.x + d.x, a.y + b.y + c.y + d.y);
            ((float2*)pooledDst)[(size_t)g * 64 + lane] = r2;
            if (LAST) {
                p4[c0] = r2.x;
                p4[c1] = r2.y;
            }
        }
        if (LAST) {
            __syncthreads();
            if (threadIdx.x < 64) {
                float acc[CC];
#pragma unroll
                for (int c = 0; c < CC; ++c) acc[c] = 0.f;
                for (int i = 0; i < LL + 1; ++i) {
                    const float* Wf = fcW + (size_t)i * DD * CC;
                    for (int k = lane; k < DD; k += 64) {
                        float pv = (i == LL) ? p4[k] : pooledAll[((size_t)i * GG + g) * DD + k];
                        const float* wr = Wf + k * CC;
#pragma unroll
                        for (int c = 0; c < CC; ++c) acc[c] = fmaf(pv, wr[c], acc[c]);
                    }
                }
#pragma unroll
                for (int c = 0; c < CC; ++c)
                    for (int off = 32; off > 0; off >>= 1) acc[c] += __shfl_down(acc[c], off);
                if (lane == 0) {
#pragma unroll
                    for (int c = 0; c < CC; ++c) {
                        float b = 0.f;
                        for (int i = 0; i < LL + 1; ++i) b += fcb[i * CC + c];
                        acc[c] += b;
                    }
                    float m = acc[0];
#pragma unroll
                    for (int c = 1; c < CC; ++c) m = fmaxf(m, acc[c]);
                    float se = 0.f;
#pragma unroll
                    for (int c = 0; c < CC; ++c) se += expf(acc[c] - m);
                    float lse = m + logf(se);
#pragma unroll
                    for (int c = 0; c < CC; ++c) out[(size_t)g * CC + c] = acc[c] - lse;
                }
            }
        }
    } else {
        int nA = (bid - GG) * 8 + (threadIdx.x >> 6) * 2;
        agg_pair<true>(nA, Z, ell, degA, stats, gamma, beta, aggOut);
    }
}

// ---------------- launch ----------------

extern "C" void kernel_launch(void* const* d_in, const int* in_sizes, int n_in,
                              void* d_out, int out_size, void* d_ws, size_t ws_size,
                              hipStream_t stream) {
    const float* x     = (const float*)d_in[0];
    const int*   ei    = (const int*)d_in[1];
    const int*   batch = (const int*)d_in[2];
    const float* Wc1   = (const float*)d_in[3];
    const float* bc1   = (const float*)d_in[4];
    const float* Wc2   = (const float*)d_in[5];
    const float* bc2   = (const float*)d_in[6];
    const float* g_mid = (const float*)d_in[7];
    const float* b_mid = (const float*)d_in[8];
    const float* g_out = (const float*)d_in[9];
    const float* b_out = (const float*)d_in[10];
    const float* fcW   = (const float*)d_in[11];
    const float* fcb   = (const float*)d_in[12];
    float* out = (float*)d_out;

    char* p = (char*)d_ws;
    unsigned short* xb   = (unsigned short*)p; p += (size_t)NN * DD * 2;
    unsigned short* aggb = (unsigned short*)p; p += (size_t)NN * DD * 2;
    unsigned short* z1b  = (unsigned short*)p; p += (size_t)NN * DD * 2;
    unsigned short* z2b  = (unsigned short*)p; p += (size_t)NN * DD * 2;
    unsigned short* WTb  = (unsigned short*)p; p += (size_t)8 * DD * DD * 2;
    float* pooled = (float*)p; p += (size_t)(LL + 1) * GG * DD * 4;
    float* statb  = (float*)p; p += 8 * 256 * 4;   // contiguous with cursor: joint zero
    int* cursor = (int*)p; p += (size_t)NN * 4;
    int* ell    = (int*)p; p += (size_t)NN * ELLW * 4;
    int* gptr   = (int*)p; p += (size_t)(GG + 16) * 4;

    const int* src = ei;
    const int* dst = ei + EE;

    zero_kernel<<<ZERO_BLOCKS, 256, 0, stream>>>((int*)statb);
    setup_kernel<<<GG + EB_BLOCKS + PW_BLOCKS + GP_BLOCKS, 256, 0, stream>>>(
        src, dst, cursor, ell, Wc1, Wc2, WTb, batch, gptr, x, xb, pooled);

    const int gemmGrid = (NN + 127) / 128;  // 391
    aggregate_x<<<AGG_BLOCKS, 256, 0, stream>>>(xb, ell, cursor, aggb);
    for (int l = 0; l < LL; ++l) {
        gemm_mfma<<<gemmGrid, 256, 0, stream>>>(
            aggb, WTb + (size_t)l * DD * DD, bc1 + (size_t)l * DD,
            nullptr, nullptr, nullptr,
            z1b, statb + (size_t)(2 * l) * 256);
        gemm_mfma<<<gemmGrid, 256, 0, stream>>>(
            z1b, WTb + (size_t)(4 + l) * DD * DD, bc2 + (size_t)l * DD,
            statb + (size_t)(2 * l) * 256, g_mid + (size_t)l * DD, b_mid + (size_t)l * DD,
            z2b, statb + (size_t)(2 * l + 1) * 256);
        if (l < LL - 1) {
            post_layer<false><<<GG + AGG_BLOCKS, 256, 0, stream>>>(
                z2b, statb + (size_t)(2 * l + 1) * 256,
                g_out + (size_t)l * DD, b_out + (size_t)l * DD,
                gptr, ell, cursor,
                pooled + (size_t)(l + 1) * GG * DD, aggb,
                nullptr, nullptr, nullptr, nullptr);
        } else {
            post_layer<true><<<GG, 256, 0, stream>>>(
                z2b, statb + (size_t)(2 * l + 1) * 256,
                g_out + (size_t)l * DD, b_out + (size_t)l * DD,
                gptr, ell, cursor,
                pooled + (size_t)(l + 1) * GG * DD, nullptr,
                pooled, fcW, fcb, out);
        }
    }
}